// Round 5
// baseline (649.359 us; speedup 1.0000x reference)
//
#include <hip/hip_runtime.h>
#include <math.h>
#include <stdint.h>

typedef __bf16 bf16_t;
typedef __bf16 bf16x8 __attribute__((ext_vector_type(8)));
typedef float f32x4 __attribute__((ext_vector_type(4)));
typedef unsigned short ushort8_t __attribute__((ext_vector_type(8)));
typedef unsigned short ushort4_t __attribute__((ext_vector_type(4)));

#define LOG2E 1.44269504088896340736f

__device__ inline unsigned short f2bf_bits(float f) {
  union { float f; unsigned int u; } v; v.f = f;
  unsigned int u = v.u;
  return (unsigned short)((u + 0x7fffu + ((u >> 16) & 1u)) >> 16);
}

// global -> LDS direct copy, 16B per lane. LDS dest is wave-uniform base
// + lane*16 (HW behavior, m104); global src is per-lane.
__device__ inline void gld_lds16(const void* g, void* l) {
  __builtin_amdgcn_global_load_lds(
      (__attribute__((address_space(1))) void*)(uintptr_t)(g),
      (__attribute__((address_space(3))) void*)(uintptr_t)(l),
      16, 0, 0);
}

// ---------------- cast fp32 -> bf16 (weights) ----------------
__global__ __launch_bounds__(256) void cast_kernel(const float* __restrict__ in,
                                                   unsigned short* __restrict__ out,
                                                   int n) {
  int i = (blockIdx.x * 256 + threadIdx.x) * 4;
  if (i >= n) return;
  float4 f = *reinterpret_cast<const float4*>(in + i);
  ushort4_t o;
  o[0] = f2bf_bits(f.x); o[1] = f2bf_bits(f.y);
  o[2] = f2bf_bits(f.z); o[3] = f2bf_bits(f.w);
  *reinterpret_cast<ushort4_t*>(out + i) = o;
}

// ---------------- LayerNorm (C=1024) + cast to bf16 ----------------
__global__ __launch_bounds__(256) void ln_kernel(const float* __restrict__ x,
                                                 const float* __restrict__ g,
                                                 const float* __restrict__ bta,
                                                 unsigned short* __restrict__ out) {
  const int row = blockIdx.x;
  const int c = threadIdx.x * 4;
  const float4 xv = *reinterpret_cast<const float4*>(x + (size_t)row * 1024 + c);
  float s = xv.x + xv.y + xv.z + xv.w;
  float sq = xv.x * xv.x + xv.y * xv.y + xv.z * xv.z + xv.w * xv.w;
#pragma unroll
  for (int xm = 1; xm < 64; xm <<= 1) {
    s += __shfl_xor(s, xm, 64);
    sq += __shfl_xor(sq, xm, 64);
  }
  __shared__ float sh[8];
  const int wave = threadIdx.x >> 6, lane = threadIdx.x & 63;
  if (lane == 0) { sh[wave] = s; sh[4 + wave] = sq; }
  __syncthreads();
  const float ts = sh[0] + sh[1] + sh[2] + sh[3];
  const float tq = sh[4] + sh[5] + sh[6] + sh[7];
  const float mean = ts * (1.0f / 1024.0f);
  const float var = tq * (1.0f / 1024.0f) - mean * mean;
  const float rstd = rsqrtf(var + 1e-5f);
  const float4 gv = *reinterpret_cast<const float4*>(g + c);
  const float4 bv = *reinterpret_cast<const float4*>(bta + c);
  ushort4_t o;
  o[0] = f2bf_bits((xv.x - mean) * rstd * gv.x + bv.x);
  o[1] = f2bf_bits((xv.y - mean) * rstd * gv.y + bv.y);
  o[2] = f2bf_bits((xv.z - mean) * rstd * gv.z + bv.z);
  o[3] = f2bf_bits((xv.w - mean) * rstd * gv.w + bv.w);
  *reinterpret_cast<ushort4_t*>(out + (size_t)row * 1024 + c) = o;
}

// ---------------- GEMM: out[m][n] = sum_k A[m][k]*W[n][k] + bias[n] ----------
// m97 verified structure: 128x128 tile, BK=32, 4 waves each 64x64,
// 16x16x32 bf16 MFMA, global_load_lds width 16, linear LDS, 2 barriers/K-step.
// EPI: 0 = bias -> bf16 out; 1 = bias + residual -> f32 out; 2 = bias+GELU -> bf16
template <int EPI>
__global__ __launch_bounds__(256) void gemm_bt(const unsigned short* __restrict__ A,
                                               const unsigned short* __restrict__ W,
                                               const float* __restrict__ bias,
                                               const float* __restrict__ res,
                                               unsigned short* __restrict__ outb,
                                               float* __restrict__ outf,
                                               int M, int N, int K) {
  __shared__ unsigned short Asb[128 * 32];
  __shared__ unsigned short Bsb[128 * 32];
  const int tid = threadIdx.x;
  const int wave = tid >> 6;
  const int lane = tid & 63;
  const int m0 = blockIdx.y * 128;
  const int n0 = blockIdx.x * 128;
  const int wm = (wave >> 1) * 64;
  const int wn = (wave & 1) * 64;

  f32x4 acc[4][4];
#pragma unroll
  for (int i = 0; i < 4; ++i)
#pragma unroll
    for (int j = 0; j < 4; ++j) { f32x4 z = {0.f, 0.f, 0.f, 0.f}; acc[i][j] = z; }

  for (int kt = 0; kt < K; kt += 32) {
#pragma unroll
    for (int i = 0; i < 2; ++i) {
      const int off = i * 4096 + wave * 1024 + lane * 16;  // byte pos in 8KB tile
      const int r = off >> 6;                              // 64B per row (BK=32)
      const int ce = (off & 63) >> 1;                      // col element
      gld_lds16(A + (size_t)(m0 + r) * K + kt + ce, &Asb[i * 2048 + wave * 512]);
      gld_lds16(W + (size_t)(n0 + r) * K + kt + ce, &Bsb[i * 2048 + wave * 512]);
    }
    __syncthreads();
    bf16x8 af[4], bfr[4];
#pragma unroll
    for (int mi = 0; mi < 4; ++mi)
      af[mi] = *reinterpret_cast<const bf16x8*>(
          &Asb[(wm + mi * 16 + (lane & 15)) * 32 + (lane >> 4) * 8]);
#pragma unroll
    for (int ni = 0; ni < 4; ++ni)
      bfr[ni] = *reinterpret_cast<const bf16x8*>(
          &Bsb[(wn + ni * 16 + (lane & 15)) * 32 + (lane >> 4) * 8]);
#pragma unroll
    for (int mi = 0; mi < 4; ++mi)
#pragma unroll
      for (int ni = 0; ni < 4; ++ni)
        acc[mi][ni] =
            __builtin_amdgcn_mfma_f32_16x16x32_bf16(af[mi], bfr[ni], acc[mi][ni], 0, 0, 0);
    __syncthreads();
  }

  // epilogue: D row=(lane>>4)*4+reg, col=lane&15 (m89/m91 verified)
#pragma unroll
  for (int ni = 0; ni < 4; ++ni) {
    const int col = n0 + wn + ni * 16 + (lane & 15);
    const float bv = bias[col];
#pragma unroll
    for (int mi = 0; mi < 4; ++mi) {
#pragma unroll
      for (int r = 0; r < 4; ++r) {
        const int row = m0 + wm + mi * 16 + ((lane >> 4) << 2) + r;
        const size_t idx = (size_t)row * N + col;
        const float v = acc[mi][ni][r] + bv;
        if (EPI == 0) {
          outb[idx] = f2bf_bits(v);
        } else if (EPI == 1) {
          outf[idx] = v + res[idx];
        } else {
          const float gl = 0.5f * v * (1.0f + erff(v * 0.70710678118654752f));
          outb[idx] = f2bf_bits(gl);
        }
      }
    }
  }
}

// ---------------- causal flash attention v2 ----------------
// kqv: [B*T][3072] bf16, per head h: k at h*192, q at h*192+64, v at h*192+128
// grid: (B*H=128, 8 pairs). block: 256 = 4 waves; wave w owns 16 q-rows of
// each of TWO q-tiles (lo=pair, hi=15-pair) -> uniform 17 compute-iters/block,
// shared K/V staging, zero causal tail. Same-bh blocks land on one XCD
// (flat%8 == bh%8) for K/V L2 reuse.
// Double-buffered K (global_load_lds) + V (T14 issue-early/write-late reg
// transpose). ONE barrier per jt; Ps is per-wave (lgkmcnt ordering only).
// XOR swizzle elem ^= (row&7)<<3 on all LDS tiles (128B rows, G4).
__device__ inline int swz(int row, int colelem) {
  return row * 64 + (colelem ^ ((row & 7) << 3));
}

__global__ __launch_bounds__(256, 4) void attn_kernel(const unsigned short* __restrict__ kqv,
                                                      unsigned short* __restrict__ y) {
  __shared__ unsigned short Ks[2][64 * 64];
  __shared__ unsigned short Vt[2][64 * 64];
  __shared__ unsigned short Ps[4][16 * 64];

  const int tid = threadIdx.x;
  const int wave = tid >> 6;
  const int lane = tid & 63;
  const int bh = blockIdx.x;
  const int pair = blockIdx.y;
  const int b = bh >> 4;
  const int h = bh & 15;
  const int lo = pair;
  const int hi = 15 - pair;
  const int bT = b * 1024;
  const int hoff = h * 192;

  // ---- helpers ----
  auto loadq = [&](int q0t, bf16x8 (&qf)[2]) {
    const unsigned short* qp =
        kqv + (size_t)(bT + q0t + wave * 16 + (lane & 15)) * 3072 + hoff + 64 +
        (lane >> 4) * 8;
#pragma unroll
    for (int kk = 0; kk < 2; ++kk) {
      bf16x8 t = *reinterpret_cast<const bf16x8*>(qp + kk * 32);
#pragma unroll
      for (int e = 0; e < 8; ++e) t[e] = (bf16_t)((float)t[e] * 0.125f);
      qf[kk] = t;
    }
  };

  auto stageK = [&](int j0, int bufi) {
#pragma unroll
    for (int i = 0; i < 2; ++i) {  // 2 x 4KB = exactly the 8KB tile (bugfix: was 4)
      const int off = i * 4096 + wave * 1024 + lane * 16;
      const int jr = off >> 7;
      const int ce = ((off & 127) >> 1) ^ ((jr & 7) << 3);
      gld_lds16(kqv + (size_t)(bT + j0 + jr) * 3072 + hoff + ce,
                &Ks[bufi][i * 2048 + wave * 512]);
    }
  };

  ushort8_t vreg0, vreg1;  // T14 issue-early / write-late staging registers
  auto vload = [&](int j0) {
    const unsigned short* vp =
        kqv + (size_t)(bT + j0 + (tid & 63)) * 3072 + hoff + 128 + (tid >> 6) * 8;
    vreg0 = *reinterpret_cast<const ushort8_t*>(vp);
    vreg1 = *reinterpret_cast<const ushort8_t*>(vp + 32);
  };
  auto vwrite = [&](int bufi) {
    const int j = tid & 63;
    const int dg = tid >> 6;
#pragma unroll
    for (int e = 0; e < 8; ++e) Vt[bufi][swz(dg * 8 + e, j)] = vreg0[e];
#pragma unroll
    for (int e = 0; e < 8; ++e) Vt[bufi][swz((dg + 4) * 8 + e, j)] = vreg1[e];
  };

  auto compute = [&](const bf16x8 (&qf)[2], f32x4 (&acc_o)[4], float (&mr)[4],
                     float (&lr)[4], int q0t, int j0, bool diag, int cur) {
    f32x4 s[4];
#pragma unroll
    for (int nt = 0; nt < 4; ++nt) {
      f32x4 a = {0.f, 0.f, 0.f, 0.f};
#pragma unroll
      for (int kk = 0; kk < 2; ++kk) {
        const bf16x8 kf = *reinterpret_cast<const bf16x8*>(
            &Ks[cur][swz(nt * 16 + (lane & 15), kk * 32 + (lane >> 4) * 8)]);
        a = __builtin_amdgcn_mfma_f32_16x16x32_bf16(qf[kk], kf, a, 0, 0, 0);
      }
      s[nt] = a;
    }
#pragma unroll
    for (int r = 0; r < 4; ++r) {
      float mx = -1e30f;
      if (diag) {
        const int qg = q0t + wave * 16 + ((lane >> 4) << 2) + r;
#pragma unroll
        for (int nt = 0; nt < 4; ++nt) {
          const int jg = j0 + nt * 16 + (lane & 15);
          const float sv = (jg <= qg) ? s[nt][r] : -1e30f;
          s[nt][r] = sv;
          mx = fmaxf(mx, sv);
        }
      } else {
#pragma unroll
        for (int nt = 0; nt < 4; ++nt) mx = fmaxf(mx, s[nt][r]);
      }
#pragma unroll
      for (int xm = 1; xm < 16; xm <<= 1) mx = fmaxf(mx, __shfl_xor(mx, xm, 64));
      const float mnew = fmaxf(mr[r], mx);
      const float sc = exp2f((mr[r] - mnew) * LOG2E);
      mr[r] = mnew;
      float ssum = 0.f;
#pragma unroll
      for (int nt = 0; nt < 4; ++nt) {
        const float p = exp2f((s[nt][r] - mnew) * LOG2E);
        s[nt][r] = p;
        ssum += p;
      }
#pragma unroll
      for (int xm = 1; xm < 16; xm <<= 1) ssum += __shfl_xor(ssum, xm, 64);
      lr[r] = lr[r] * sc + ssum;
#pragma unroll
      for (int dt = 0; dt < 4; ++dt) acc_o[dt][r] *= sc;
    }
    // P -> per-wave LDS (same-wave RAW; no barrier, lgkmcnt only)
    unsigned short* Pw = &Ps[wave][0];
#pragma unroll
    for (int nt = 0; nt < 4; ++nt)
#pragma unroll
      for (int r = 0; r < 4; ++r)
        Pw[swz(((lane >> 4) << 2) + r, nt * 16 + (lane & 15))] = f2bf_bits(s[nt][r]);
#pragma unroll
    for (int kk = 0; kk < 2; ++kk) {
      const bf16x8 pf = *reinterpret_cast<const bf16x8*>(
          &Ps[wave][swz(lane & 15, kk * 32 + (lane >> 4) * 8)]);
#pragma unroll
      for (int dt = 0; dt < 4; ++dt) {
        const bf16x8 vf = *reinterpret_cast<const bf16x8*>(
            &Vt[cur][swz(dt * 16 + (lane & 15), kk * 32 + (lane >> 4) * 8)]);
        acc_o[dt] = __builtin_amdgcn_mfma_f32_16x16x32_bf16(pf, vf, acc_o[dt], 0, 0, 0);
      }
    }
  };

  auto writeo = [&](int q0t, f32x4 (&acc_o)[4], float (&lr)[4]) {
#pragma unroll
    for (int dt = 0; dt < 4; ++dt)
#pragma unroll
      for (int r = 0; r < 4; ++r) {
        const int qg = q0t + wave * 16 + ((lane >> 4) << 2) + r;
        y[(size_t)(bT + qg) * 1024 + h * 64 + dt * 16 + (lane & 15)] =
            f2bf_bits(acc_o[dt][r] / lr[r]);
      }
  };

  // ---- state for both q-tiles ----
  bf16x8 qf_l[2], qf_h[2];
  loadq(lo * 64, qf_l);
  loadq(hi * 64, qf_h);
  f32x4 acc_l[4], acc_h[4];
#pragma unroll
  for (int dt = 0; dt < 4; ++dt) {
    f32x4 z = {0.f, 0.f, 0.f, 0.f};
    acc_l[dt] = z;
    acc_h[dt] = z;
  }
  float mr_l[4] = {-1e30f, -1e30f, -1e30f, -1e30f};
  float mr_h[4] = {-1e30f, -1e30f, -1e30f, -1e30f};
  float lr_l[4] = {0.f, 0.f, 0.f, 0.f};
  float lr_h[4] = {0.f, 0.f, 0.f, 0.f};

  // ---- prologue: stage tile 0 into buffer 0 ----
  stageK(0, 0);
  vload(0);
  vwrite(0);

  // ---- main loop: one barrier per jt, staging overlapped with compute ----
  for (int jt = 0; jt <= hi; ++jt) {
    const int cur = jt & 1;
    __syncthreads();  // buf[cur] ready (vmcnt+lgkm drained); buf[cur^1] free
    if (jt < hi) {
      stageK((jt + 1) * 64, cur ^ 1);  // async into other buffer
      vload((jt + 1) * 64);            // issue early...
    }
    compute(qf_h, acc_h, mr_h, lr_h, hi * 64, jt * 64, jt == hi, cur);
    if (jt <= lo)
      compute(qf_l, acc_l, mr_l, lr_l, lo * 64, jt * 64, jt == lo, cur);
    if (jt < hi) vwrite(cur ^ 1);      // ...write late (latency hidden)
  }

  writeo(hi * 64, acc_h, lr_h);
  writeo(lo * 64, acc_l, lr_l);
}

// ---------------- launch ----------------
extern "C" void kernel_launch(void* const* d_in, const int* in_sizes, int n_in,
                              void* d_out, int out_size, void* d_ws, size_t ws_size,
                              hipStream_t stream) {
  const float* x = (const float*)d_in[0];
  const float* kqv_w = (const float*)d_in[1];
  const float* kqv_b = (const float*)d_in[2];
  const float* proj_w = (const float*)d_in[3];
  const float* proj_b = (const float*)d_in[4];
  const float* ln1_g = (const float*)d_in[5];
  const float* ln1_b = (const float*)d_in[6];
  const float* ln2_g = (const float*)d_in[7];
  const float* ln2_b = (const float*)d_in[8];
  const float* fc1_w = (const float*)d_in[9];
  const float* fc1_b = (const float*)d_in[10];
  const float* fc2_w = (const float*)d_in[11];
  const float* fc2_b = (const float*)d_in[12];
  float* out = (float*)d_out;

  char* ws = (char*)d_ws;
  size_t off = 0;
  auto alloc = [&](size_t bytes) {
    char* p = ws + off;
    off += (bytes + 255) & ~(size_t)255;
    return p;
  };
  unsigned short* wk = (unsigned short*)alloc((size_t)3072 * 1024 * 2);
  unsigned short* wp = (unsigned short*)alloc((size_t)1024 * 1024 * 2);
  unsigned short* w1 = (unsigned short*)alloc((size_t)4096 * 1024 * 2);
  unsigned short* w2 = (unsigned short*)alloc((size_t)4096 * 1024 * 2);
  unsigned short* hbuf = (unsigned short*)alloc((size_t)8192 * 1024 * 2);  // LN1 out, reused for LN2 out
  unsigned short* kqvb = (unsigned short*)alloc((size_t)8192 * 3072 * 2);
  unsigned short* yb = (unsigned short*)alloc((size_t)8192 * 1024 * 2);
  float* x1 = (float*)alloc((size_t)8192 * 1024 * 4);
  unsigned short* a1 = (unsigned short*)alloc((size_t)8192 * 4096 * 2);

  // cast weights to bf16
  cast_kernel<<<dim3(3072 * 1024 / 1024), 256, 0, stream>>>(kqv_w, wk, 3072 * 1024);
  cast_kernel<<<dim3(1024 * 1024 / 1024), 256, 0, stream>>>(proj_w, wp, 1024 * 1024);
  cast_kernel<<<dim3(4096 * 1024 / 1024), 256, 0, stream>>>(fc1_w, w1, 4096 * 1024);
  cast_kernel<<<dim3(4096 * 1024 / 1024), 256, 0, stream>>>(fc2_w, w2, 4096 * 1024);

  // LN1 -> h (bf16)
  ln_kernel<<<dim3(8192), 256, 0, stream>>>(x, ln1_g, ln1_b, hbuf);

  // kqv = h @ kqv_w^T + b   [8192 x 3072]
  gemm_bt<0><<<dim3(3072 / 128, 8192 / 128), 256, 0, stream>>>(
      hbuf, wk, kqv_b, nullptr, kqvb, nullptr, 8192, 3072, 1024);

  // attention -> y (bf16). grid: (bh, pair) so same-bh blocks share an XCD L2.
  attn_kernel<<<dim3(128, 8), 256, 0, stream>>>(kqvb, yb);

  // x1 = x + y @ proj_w^T + b   (fp32)
  gemm_bt<1><<<dim3(1024 / 128, 8192 / 128), 256, 0, stream>>>(
      yb, wp, proj_b, x, nullptr, x1, 8192, 1024, 1024);

  // LN2 -> h (bf16, reuse)
  ln_kernel<<<dim3(8192), 256, 0, stream>>>(x1, ln2_g, ln2_b, hbuf);

  // a1 = gelu(h @ fc1_w^T + b)  [8192 x 4096] bf16
  gemm_bt<2><<<dim3(4096 / 128, 8192 / 128), 256, 0, stream>>>(
      hbuf, w1, fc1_b, nullptr, a1, nullptr, 8192, 4096, 1024);

  // out = x1 + a1 @ fc2_w^T + b  (fp32)
  gemm_bt<1><<<dim3(1024 / 128, 8192 / 128), 256, 0, stream>>>(
      a1, w2, fc2_b, x1, nullptr, out, 8192, 1024, 4096);
}

// Round 6
// 533.414 us; speedup vs baseline: 1.2174x; 1.2174x over previous
//
#include <hip/hip_runtime.h>
#include <math.h>
#include <stdint.h>

typedef __bf16 bf16_t;
typedef __bf16 bf16x8 __attribute__((ext_vector_type(8)));
typedef float f32x4 __attribute__((ext_vector_type(4)));
typedef unsigned short ushort8_t __attribute__((ext_vector_type(8)));
typedef unsigned short ushort4_t __attribute__((ext_vector_type(4)));

#define LOG2E 1.44269504088896340736f

__device__ inline unsigned short f2bf_bits(float f) {
  union { float f; unsigned int u; } v; v.f = f;
  unsigned int u = v.u;
  return (unsigned short)((u + 0x7fffu + ((u >> 16) & 1u)) >> 16);
}

// global -> LDS direct copy, 16B per lane. LDS dest is wave-uniform base
// + lane*16 (HW behavior, m104); global src is per-lane.
__device__ inline void gld_lds16(const void* g, void* l) {
  __builtin_amdgcn_global_load_lds(
      (__attribute__((address_space(1))) void*)(uintptr_t)(g),
      (__attribute__((address_space(3))) void*)(uintptr_t)(l),
      16, 0, 0);
}

#define BAR() __builtin_amdgcn_s_barrier()
#define LGKM0() asm volatile("s_waitcnt lgkmcnt(0)" ::: "memory")
#define VMW(n) asm volatile("s_waitcnt vmcnt(" #n ")" ::: "memory")
#define PRIO(p) __builtin_amdgcn_s_setprio(p)

// ---------------- cast fp32 -> bf16 (weights) ----------------
__global__ __launch_bounds__(256) void cast_kernel(const float* __restrict__ in,
                                                   unsigned short* __restrict__ out,
                                                   int n) {
  int i = (blockIdx.x * 256 + threadIdx.x) * 4;
  if (i >= n) return;
  float4 f = *reinterpret_cast<const float4*>(in + i);
  ushort4_t o;
  o[0] = f2bf_bits(f.x); o[1] = f2bf_bits(f.y);
  o[2] = f2bf_bits(f.z); o[3] = f2bf_bits(f.w);
  *reinterpret_cast<ushort4_t*>(out + i) = o;
}

// ---------------- LayerNorm (C=1024) + cast to bf16 ----------------
__global__ __launch_bounds__(256) void ln_kernel(const float* __restrict__ x,
                                                 const float* __restrict__ g,
                                                 const float* __restrict__ bta,
                                                 unsigned short* __restrict__ out) {
  const int row = blockIdx.x;
  const int c = threadIdx.x * 4;
  const float4 xv = *reinterpret_cast<const float4*>(x + (size_t)row * 1024 + c);
  float s = xv.x + xv.y + xv.z + xv.w;
  float sq = xv.x * xv.x + xv.y * xv.y + xv.z * xv.z + xv.w * xv.w;
#pragma unroll
  for (int xm = 1; xm < 64; xm <<= 1) {
    s += __shfl_xor(s, xm, 64);
    sq += __shfl_xor(sq, xm, 64);
  }
  __shared__ float sh[8];
  const int wave = threadIdx.x >> 6, lane = threadIdx.x & 63;
  if (lane == 0) { sh[wave] = s; sh[4 + wave] = sq; }
  __syncthreads();
  const float ts = sh[0] + sh[1] + sh[2] + sh[3];
  const float tq = sh[4] + sh[5] + sh[6] + sh[7];
  const float mean = ts * (1.0f / 1024.0f);
  const float var = tq * (1.0f / 1024.0f) - mean * mean;
  const float rstd = rsqrtf(var + 1e-5f);
  const float4 gv = *reinterpret_cast<const float4*>(g + c);
  const float4 bv = *reinterpret_cast<const float4*>(bta + c);
  ushort4_t o;
  o[0] = f2bf_bits((xv.x - mean) * rstd * gv.x + bv.x);
  o[1] = f2bf_bits((xv.y - mean) * rstd * gv.y + bv.y);
  o[2] = f2bf_bits((xv.z - mean) * rstd * gv.z + bv.z);
  o[3] = f2bf_bits((xv.w - mean) * rstd * gv.w + bv.w);
  *reinterpret_cast<ushort4_t*>(out + (size_t)row * 1024 + c) = o;
}

// ---------------- GEMM m97 structure (kept for proj / fc2) -----------------
// EPI: 0 = bias -> bf16 out; 1 = bias + residual -> f32 out; 2 = bias+GELU -> bf16
template <int EPI>
__global__ __launch_bounds__(256) void gemm_bt(const unsigned short* __restrict__ A,
                                               const unsigned short* __restrict__ W,
                                               const float* __restrict__ bias,
                                               const float* __restrict__ res,
                                               unsigned short* __restrict__ outb,
                                               float* __restrict__ outf,
                                               int M, int N, int K) {
  __shared__ unsigned short Asb[128 * 32];
  __shared__ unsigned short Bsb[128 * 32];
  const int tid = threadIdx.x;
  const int wave = tid >> 6;
  const int lane = tid & 63;
  const int m0 = blockIdx.y * 128;
  const int n0 = blockIdx.x * 128;
  const int wm = (wave >> 1) * 64;
  const int wn = (wave & 1) * 64;

  f32x4 acc[4][4];
#pragma unroll
  for (int i = 0; i < 4; ++i)
#pragma unroll
    for (int j = 0; j < 4; ++j) { f32x4 z = {0.f, 0.f, 0.f, 0.f}; acc[i][j] = z; }

  for (int kt = 0; kt < K; kt += 32) {
#pragma unroll
    for (int i = 0; i < 2; ++i) {
      const int off = i * 4096 + wave * 1024 + lane * 16;  // byte pos in 8KB tile
      const int r = off >> 6;                              // 64B per row (BK=32)
      const int ce = (off & 63) >> 1;                      // col element
      gld_lds16(A + (size_t)(m0 + r) * K + kt + ce, &Asb[i * 2048 + wave * 512]);
      gld_lds16(W + (size_t)(n0 + r) * K + kt + ce, &Bsb[i * 2048 + wave * 512]);
    }
    __syncthreads();
    bf16x8 af[4], bfr[4];
#pragma unroll
    for (int mi = 0; mi < 4; ++mi)
      af[mi] = *reinterpret_cast<const bf16x8*>(
          &Asb[(wm + mi * 16 + (lane & 15)) * 32 + (lane >> 4) * 8]);
#pragma unroll
    for (int ni = 0; ni < 4; ++ni)
      bfr[ni] = *reinterpret_cast<const bf16x8*>(
          &Bsb[(wn + ni * 16 + (lane & 15)) * 32 + (lane >> 4) * 8]);
#pragma unroll
    for (int mi = 0; mi < 4; ++mi)
#pragma unroll
      for (int ni = 0; ni < 4; ++ni)
        acc[mi][ni] =
            __builtin_amdgcn_mfma_f32_16x16x32_bf16(af[mi], bfr[ni], acc[mi][ni], 0, 0, 0);
    __syncthreads();
  }

#pragma unroll
  for (int ni = 0; ni < 4; ++ni) {
    const int col = n0 + wn + ni * 16 + (lane & 15);
    const float bv = bias[col];
#pragma unroll
    for (int mi = 0; mi < 4; ++mi) {
#pragma unroll
      for (int r = 0; r < 4; ++r) {
        const int row = m0 + wm + mi * 16 + ((lane >> 4) << 2) + r;
        const size_t idx = (size_t)row * N + col;
        const float v = acc[mi][ni][r] + bv;
        if (EPI == 0) {
          outb[idx] = f2bf_bits(v);
        } else if (EPI == 1) {
          outf[idx] = v + res[idx];
        } else {
          const float gl = 0.5f * v * (1.0f + erff(v * 0.70710678118654752f));
          outb[idx] = f2bf_bits(gl);
        }
      }
    }
  }
}

// ---------------- GEMM 256x256 8-phase (T2+T3+T4+T5), out = A@W^T + bias ----
// 512 threads = 8 waves (2M x 4N), per-wave 128x64 output, acc[8][4] f32x4.
// BK=64; LDS = 2 slots x {A,B} x 2 halves x (128x64 bf16) = 128 KiB ring.
// Staging: global_load_lds w16, LINEAR dest, st_16x32 swizzle via pre-swizzled
// global source (rule #21); ds_read applies the same involution.
// Per phase: {ds_read quadrant frags | stage 1 half-tile} barrier lgkm(0)
// setprio(1) 16xMFMA setprio(0) barrier. vmcnt(4) ONLY at phases 4/8 (T4).
// Every LDS region has >=1 barrier-separated phase between last read and
// overwrite (verified schedule; see staging plan in phase comments).
#define MMA16(QM, QN, AF, BF)                                                 \
  do {                                                                        \
    _Pragma("unroll") for (int mi_ = 0; mi_ < 4; ++mi_)                       \
    _Pragma("unroll") for (int ni_ = 0; ni_ < 2; ++ni_)                       \
    _Pragma("unroll") for (int kh_ = 0; kh_ < 2; ++kh_)                       \
      acc[(QM) * 4 + mi_][(QN) * 2 + ni_] =                                   \
          __builtin_amdgcn_mfma_f32_16x16x32_bf16(                            \
              AF[mi_][kh_], BF[ni_][kh_],                                     \
              acc[(QM) * 4 + mi_][(QN) * 2 + ni_], 0, 0, 0);                  \
  } while (0)

#define LDA4(DST, BASE, QM)                                                   \
  do {                                                                        \
    _Pragma("unroll") for (int mi_ = 0; mi_ < 4; ++mi_)                       \
    _Pragma("unroll") for (int kh_ = 0; kh_ < 2; ++kh_) {                     \
      const int row_ = ((QM) * 4 + mi_) * 16 + lr16;                          \
      const int cb_ = (kh_ * 64 + lk * 16) ^ (((row_ >> 2) & 1) << 5);        \
      DST[mi_][kh_] =                                                         \
          *reinterpret_cast<const bf16x8*>(&lds[(BASE) + row_ * 64 + (cb_ >> 1)]); \
    }                                                                         \
  } while (0)

#define LDB2(DST, BASE, QN)                                                   \
  do {                                                                        \
    _Pragma("unroll") for (int ni_ = 0; ni_ < 2; ++ni_)                       \
    _Pragma("unroll") for (int kh_ = 0; kh_ < 2; ++kh_) {                     \
      const int row_ = (wn & 1) * 64 + ((QN) * 2 + ni_) * 16 + lr16;          \
      const int cb_ = (kh_ * 64 + lk * 16) ^ (((row_ >> 2) & 1) << 5);        \
      DST[ni_][kh_] =                                                         \
          *reinterpret_cast<const bf16x8*>(&lds[(BASE) + row_ * 64 + (cb_ >> 1)]); \
    }                                                                         \
  } while (0)

template <int EPI>  // 0 = bias->bf16, 2 = bias+GELU->bf16
__global__ __launch_bounds__(512, 2) void gemm256(const unsigned short* __restrict__ A,
                                                  const unsigned short* __restrict__ W,
                                                  const float* __restrict__ bias,
                                                  unsigned short* __restrict__ outb,
                                                  int N, int K) {
  __shared__ unsigned short lds[65536];  // 128 KiB
  const int tid = threadIdx.x;
  const int w = tid >> 6;
  const int l = tid & 63;
  const int m0 = blockIdx.y * 256;
  const int n0 = blockIdx.x * 256;
  const int wm = w >> 2;  // 0..1
  const int wn = w & 3;   // 0..3
  const int lr16 = l & 15;
  const int lk = l >> 4;  // 0..3

  // staging per-lane geometry: linear off = i*8192 + w*1024 + l*16 bytes
  // row = i*64 + w*8 + (l>>3); src col pre-swizzled (involution of st_16x32)
  const int srow = l >> 3;
  const int scol = ((l & 7) << 3) ^ (((l >> 5) & 1) << 4);  // element offset

  auto stageA = [&](int t, int h) {
    const int s_ = t & 1;
#pragma unroll
    for (int i = 0; i < 2; ++i)
      gld_lds16(A + (size_t)(m0 + h * 128 + i * 64 + w * 8 + srow) * K + t * 64 + scol,
                &lds[(s_ * 2 + h) * 8192 + i * 4096 + w * 512]);
  };
  auto stageB = [&](int t, int h) {
    const int s_ = t & 1;
#pragma unroll
    for (int i = 0; i < 2; ++i)
      gld_lds16(W + (size_t)(n0 + h * 128 + i * 64 + w * 8 + srow) * K + t * 64 + scol,
                &lds[(4 + s_ * 2 + h) * 8192 + i * 4096 + w * 512]);
  };

  const int abase0 = wm * 8192;            // A slot0, half wm
  const int abase1 = (2 + wm) * 8192;      // A slot1
  const int bbase0 = (4 + (wn >> 1)) * 8192;
  const int bbase1 = (6 + (wn >> 1)) * 8192;

  f32x4 acc[8][4];
#pragma unroll
  for (int i = 0; i < 8; ++i)
#pragma unroll
    for (int j = 0; j < 4; ++j) { f32x4 z = {0.f, 0.f, 0.f, 0.f}; acc[i][j] = z; }

  bf16x8 a0[4][2], a1[4][2], b0[2][2], b1[2][2];

  // prologue: tile0 (A,B) + tile1 A; vmcnt(4) leaves A(1) in flight
  stageA(0, 0); stageA(0, 1);
  stageB(0, 0); stageB(0, 1);
  stageA(1, 0); stageA(1, 1);
  VMW(4);
  BAR();

  const int nt = K / 64;  // even (K multiple of 128)
  for (int t0 = 0; t0 < nt; t0 += 2) {
    const int t1 = t0 + 1;
    const int tn0 = (t0 + 2 < nt) ? (t0 + 2) : 0;  // clamp keeps even parity
    const int tn1 = (t0 + 3 < nt) ? (t0 + 3) : 1;  // clamp keeps odd parity

    // ph1: slot0 q(0,0); stage B(t1)h0   [B-slot1 last read prev ph7]
    LDA4(a0, abase0, 0);
    LDB2(b0, bbase0, 0);
    stageB(t1, 0);
    BAR(); LGKM0(); PRIO(1); MMA16(0, 0, a0, b0); PRIO(0); BAR();
    // ph2: slot0 q(1,0); stage B(t1)h1
    LDA4(a1, abase0, 1);
    stageB(t1, 1);
    BAR(); LGKM0(); PRIO(1); MMA16(1, 0, a1, b0); PRIO(0); BAR();
    // ph3: slot0 q(1,1); stage A(t0+2)h0  [A-slot0 reads ended ph2]
    LDB2(b1, bbase0, 1);
    stageA(tn0, 0);
    BAR(); LGKM0(); PRIO(1); MMA16(1, 1, a1, b1); PRIO(0); BAR();
    // ph4: slot0 q(0,1); stage A(t0+2)h1; vmcnt(4) -> slot1 (A prev ph7/8,
    // B this ph1/2) fully landed before ph5 reads
    stageA(tn0, 1);
    BAR(); LGKM0(); PRIO(1); MMA16(0, 1, a0, b1); PRIO(0);
    VMW(4);
    BAR();
    // ph5: slot1 q(0,0); stage B(t0+2)h0  [B-slot0 reads ended ph3]
    LDA4(a0, abase1, 0);
    LDB2(b0, bbase1, 0);
    stageB(tn0, 0);
    BAR(); LGKM0(); PRIO(1); MMA16(0, 0, a0, b0); PRIO(0); BAR();
    // ph6: slot1 q(1,0); stage B(t0+2)h1
    LDA4(a1, abase1, 1);
    stageB(tn0, 1);
    BAR(); LGKM0(); PRIO(1); MMA16(1, 0, a1, b0); PRIO(0); BAR();
    // ph7: slot1 q(1,1); stage A(t1+2)h0  [A-slot1 reads ended ph6]
    LDB2(b1, bbase1, 1);
    stageA(tn1, 0);
    BAR(); LGKM0(); PRIO(1); MMA16(1, 1, a1, b1); PRIO(0); BAR();
    // ph8: slot1 q(0,1); stage A(t1+2)h1; vmcnt(4) -> slot0 (ph3..6) landed
    stageA(tn1, 1);
    BAR(); LGKM0(); PRIO(1); MMA16(0, 1, a0, b1); PRIO(0);
    VMW(4);
    BAR();
  }
  VMW(0);  // drain dangling prefetches before LDS goes away

  // epilogue: C row=(l>>4)*4+r, col=l&15 per 16x16 fragment (m89/m91)
#pragma unroll
  for (int ni = 0; ni < 4; ++ni) {
    const int col = n0 + wn * 64 + ni * 16 + lr16;
    const float bv = bias[col];
#pragma unroll
    for (int mi = 0; mi < 8; ++mi) {
#pragma unroll
      for (int r = 0; r < 4; ++r) {
        const int row = m0 + wm * 128 + mi * 16 + lk * 4 + r;
        float v = acc[mi][ni][r] + bv;
        if (EPI == 2) v = 0.5f * v * (1.0f + erff(v * 0.70710678118654752f));
        outb[(size_t)row * N + col] = f2bf_bits(v);
      }
    }
  }
}

// ---------------- causal flash attention v2 (paired q-tiles) ----------------
// Same structure as round 5; spill fix: NO min-waves clause in launch_bounds
// (the (256,4) forced VGPR 64 -> ~40 regs of loop state spilled to scratch:
// 527MB FETCH / 335MB WRITE. Natural allocation ~115-125 VGPR still gives
// 4 waves/SIMD per m69 occupancy steps.)
__device__ inline int swz(int row, int colelem) {
  return row * 64 + (colelem ^ ((row & 7) << 3));
}

__global__ __launch_bounds__(256) void attn_kernel(const unsigned short* __restrict__ kqv,
                                                   unsigned short* __restrict__ y) {
  __shared__ unsigned short Ks[2][64 * 64];
  __shared__ unsigned short Vt[2][64 * 64];
  __shared__ unsigned short Ps[4][16 * 64];

  const int tid = threadIdx.x;
  const int wave = tid >> 6;
  const int lane = tid & 63;
  const int bh = blockIdx.x;
  const int pair = blockIdx.y;
  const int b = bh >> 4;
  const int h = bh & 15;
  const int lo = pair;
  const int hi = 15 - pair;
  const int bT = b * 1024;
  const int hoff = h * 192;

  auto loadq = [&](int q0t, bf16x8 (&qf)[2]) {
    const unsigned short* qp =
        kqv + (size_t)(bT + q0t + wave * 16 + (lane & 15)) * 3072 + hoff + 64 +
        (lane >> 4) * 8;
#pragma unroll
    for (int kk = 0; kk < 2; ++kk) {
      bf16x8 t = *reinterpret_cast<const bf16x8*>(qp + kk * 32);
#pragma unroll
      for (int e = 0; e < 8; ++e) t[e] = (bf16_t)((float)t[e] * 0.125f);
      qf[kk] = t;
    }
  };

  auto stageK = [&](int j0, int bufi) {
#pragma unroll
    for (int i = 0; i < 2; ++i) {
      const int off = i * 4096 + wave * 1024 + lane * 16;
      const int jr = off >> 7;
      const int ce = ((off & 127) >> 1) ^ ((jr & 7) << 3);
      gld_lds16(kqv + (size_t)(bT + j0 + jr) * 3072 + hoff + ce,
                &Ks[bufi][i * 2048 + wave * 512]);
    }
  };

  ushort8_t vreg0, vreg1;
  auto vload = [&](int j0) {
    const unsigned short* vp =
        kqv + (size_t)(bT + j0 + (tid & 63)) * 3072 + hoff + 128 + (tid >> 6) * 8;
    vreg0 = *reinterpret_cast<const ushort8_t*>(vp);
    vreg1 = *reinterpret_cast<const ushort8_t*>(vp + 32);
  };
  auto vwrite = [&](int bufi) {
    const int j = tid & 63;
    const int dg = tid >> 6;
#pragma unroll
    for (int e = 0; e < 8; ++e) Vt[bufi][swz(dg * 8 + e, j)] = vreg0[e];
#pragma unroll
    for (int e = 0; e < 8; ++e) Vt[bufi][swz((dg + 4) * 8 + e, j)] = vreg1[e];
  };

  auto compute = [&](const bf16x8 (&qf)[2], f32x4 (&acc_o)[4], float (&mr)[4],
                     float (&lr)[4], int q0t, int j0, bool diag, int cur) {
    f32x4 s[4];
#pragma unroll
    for (int nt = 0; nt < 4; ++nt) {
      f32x4 a = {0.f, 0.f, 0.f, 0.f};
#pragma unroll
      for (int kk = 0; kk < 2; ++kk) {
        const bf16x8 kf = *reinterpret_cast<const bf16x8*>(
            &Ks[cur][swz(nt * 16 + (lane & 15), kk * 32 + (lane >> 4) * 8)]);
        a = __builtin_amdgcn_mfma_f32_16x16x32_bf16(qf[kk], kf, a, 0, 0, 0);
      }
      s[nt] = a;
    }
#pragma unroll
    for (int r = 0; r < 4; ++r) {
      float mx = -1e30f;
      if (diag) {
        const int qg = q0t + wave * 16 + ((lane >> 4) << 2) + r;
#pragma unroll
        for (int nt = 0; nt < 4; ++nt) {
          const int jg = j0 + nt * 16 + (lane & 15);
          const float sv = (jg <= qg) ? s[nt][r] : -1e30f;
          s[nt][r] = sv;
          mx = fmaxf(mx, sv);
        }
      } else {
#pragma unroll
        for (int nt = 0; nt < 4; ++nt) mx = fmaxf(mx, s[nt][r]);
      }
#pragma unroll
      for (int xm = 1; xm < 16; xm <<= 1) mx = fmaxf(mx, __shfl_xor(mx, xm, 64));
      const float mnew = fmaxf(mr[r], mx);
      const float sc = exp2f((mr[r] - mnew) * LOG2E);
      mr[r] = mnew;
      float ssum = 0.f;
#pragma unroll
      for (int nt = 0; nt < 4; ++nt) {
        const float p = exp2f((s[nt][r] - mnew) * LOG2E);
        s[nt][r] = p;
        ssum += p;
      }
#pragma unroll
      for (int xm = 1; xm < 16; xm <<= 1) ssum += __shfl_xor(ssum, xm, 64);
      lr[r] = lr[r] * sc + ssum;
#pragma unroll
      for (int dt = 0; dt < 4; ++dt) acc_o[dt][r] *= sc;
    }
    unsigned short* Pw = &Ps[wave][0];
#pragma unroll
    for (int nt = 0; nt < 4; ++nt)
#pragma unroll
      for (int r = 0; r < 4; ++r)
        Pw[swz(((lane >> 4) << 2) + r, nt * 16 + (lane & 15))] = f2bf_bits(s[nt][r]);
#pragma unroll
    for (int kk = 0; kk < 2; ++kk) {
      const bf16x8 pf = *reinterpret_cast<const bf16x8*>(
          &Ps[wave][swz(lane & 15, kk * 32 + (lane >> 4) * 8)]);
#pragma unroll
      for (int dt = 0; dt < 4; ++dt) {
        const bf16x8 vf = *reinterpret_cast<const bf16x8*>(
            &Vt[cur][swz(dt * 16 + (lane & 15), kk * 32 + (lane >> 4) * 8)]);
        acc_o[dt] = __builtin_amdgcn_mfma_f32_16x16x32_bf16(pf, vf, acc_o[dt], 0, 0, 0);
      }
    }
  };

  auto writeo = [&](int q0t, f32x4 (&acc_o)[4], float (&lr)[4]) {
#pragma unroll
    for (int dt = 0; dt < 4; ++dt)
#pragma unroll
      for (int r = 0; r < 4; ++r) {
        const int qg = q0t + wave * 16 + ((lane >> 4) << 2) + r;
        y[(size_t)(bT + qg) * 1024 + h * 64 + dt * 16 + (lane & 15)] =
            f2bf_bits(acc_o[dt][r] / lr[r]);
      }
  };

  bf16x8 qf_l[2], qf_h[2];
  loadq(lo * 64, qf_l);
  loadq(hi * 64, qf_h);
  f32x4 acc_l[4], acc_h[4];
#pragma unroll
  for (int dt = 0; dt < 4; ++dt) {
    f32x4 z = {0.f, 0.f, 0.f, 0.f};
    acc_l[dt] = z;
    acc_h[dt] = z;
  }
  float mr_l[4] = {-1e30f, -1e30f, -1e30f, -1e30f};
  float mr_h[4] = {-1e30f, -1e30f, -1e30f, -1e30f};
  float lr_l[4] = {0.f, 0.f, 0.f, 0.f};
  float lr_h[4] = {0.f, 0.f, 0.f, 0.f};

  stageK(0, 0);
  vload(0);
  vwrite(0);

  for (int jt = 0; jt <= hi; ++jt) {
    const int cur = jt & 1;
    __syncthreads();  // drains vmcnt/lgkm: buf[cur] ready; buf[cur^1] free
    if (jt < hi) {
      stageK((jt + 1) * 64, cur ^ 1);
      vload((jt + 1) * 64);
    }
    compute(qf_h, acc_h, mr_h, lr_h, hi * 64, jt * 64, jt == hi, cur);
    if (jt <= lo)
      compute(qf_l, acc_l, mr_l, lr_l, lo * 64, jt * 64, jt == lo, cur);
    if (jt < hi) vwrite(cur ^ 1);
  }

  writeo(hi * 64, acc_h, lr_h);
  writeo(lo * 64, acc_l, lr_l);
}

// ---------------- launch ----------------
extern "C" void kernel_launch(void* const* d_in, const int* in_sizes, int n_in,
                              void* d_out, int out_size, void* d_ws, size_t ws_size,
                              hipStream_t stream) {
  const float* x = (const float*)d_in[0];
  const float* kqv_w = (const float*)d_in[1];
  const float* kqv_b = (const float*)d_in[2];
  const float* proj_w = (const float*)d_in[3];
  const float* proj_b = (const float*)d_in[4];
  const float* ln1_g = (const float*)d_in[5];
  const float* ln1_b = (const float*)d_in[6];
  const float* ln2_g = (const float*)d_in[7];
  const float* ln2_b = (const float*)d_in[8];
  const float* fc1_w = (const float*)d_in[9];
  const float* fc1_b = (const float*)d_in[10];
  const float* fc2_w = (const float*)d_in[11];
  const float* fc2_b = (const float*)d_in[12];
  float* out = (float*)d_out;

  char* ws = (char*)d_ws;
  size_t off = 0;
  auto alloc = [&](size_t bytes) {
    char* p = ws + off;
    off += (bytes + 255) & ~(size_t)255;
    return p;
  };
  unsigned short* wk = (unsigned short*)alloc((size_t)3072 * 1024 * 2);
  unsigned short* wp = (unsigned short*)alloc((size_t)1024 * 1024 * 2);
  unsigned short* w1 = (unsigned short*)alloc((size_t)4096 * 1024 * 2);
  unsigned short* w2 = (unsigned short*)alloc((size_t)4096 * 1024 * 2);
  unsigned short* hbuf = (unsigned short*)alloc((size_t)8192 * 1024 * 2);
  unsigned short* kqvb = (unsigned short*)alloc((size_t)8192 * 3072 * 2);
  unsigned short* yb = (unsigned short*)alloc((size_t)8192 * 1024 * 2);
  float* x1 = (float*)alloc((size_t)8192 * 1024 * 4);
  unsigned short* a1 = (unsigned short*)alloc((size_t)8192 * 4096 * 2);

  // cast weights to bf16
  cast_kernel<<<dim3(3072 * 1024 / 1024), 256, 0, stream>>>(kqv_w, wk, 3072 * 1024);
  cast_kernel<<<dim3(1024 * 1024 / 1024), 256, 0, stream>>>(proj_w, wp, 1024 * 1024);
  cast_kernel<<<dim3(4096 * 1024 / 1024), 256, 0, stream>>>(fc1_w, w1, 4096 * 1024);
  cast_kernel<<<dim3(4096 * 1024 / 1024), 256, 0, stream>>>(fc2_w, w2, 4096 * 1024);

  // LN1 -> h (bf16)
  ln_kernel<<<dim3(8192), 256, 0, stream>>>(x, ln1_g, ln1_b, hbuf);

  // kqv = h @ kqv_w^T + b   [8192 x 3072]   (8-phase 256^2)
  gemm256<0><<<dim3(3072 / 256, 8192 / 256), 512, 0, stream>>>(
      hbuf, wk, kqv_b, kqvb, 3072, 1024);

  // attention -> y (bf16)
  attn_kernel<<<dim3(128, 8), 256, 0, stream>>>(kqvb, yb);

  // x1 = x + y @ proj_w^T + b   (fp32)  (m97 128^2: N=1024 grid too small for 256^2)
  gemm_bt<1><<<dim3(1024 / 128, 8192 / 128), 256, 0, stream>>>(
      yb, wp, proj_b, x, nullptr, x1, 8192, 1024, 1024);

  // LN2 -> h (bf16, reuse)
  ln_kernel<<<dim3(8192), 256, 0, stream>>>(x1, ln2_g, ln2_b, hbuf);

  // a1 = gelu(h @ fc1_w^T + b)  [8192 x 4096] bf16   (8-phase 256^2)
  gemm256<2><<<dim3(4096 / 256, 8192 / 256), 512, 0, stream>>>(
      hbuf, w1, fc1_b, a1, 4096, 1024);

  // out = x1 + a1 @ fc2_w^T + b  (fp32)  (m97 128^2: N=1024)
  gemm_bt<1><<<dim3(1024 / 128, 8192 / 128), 256, 0, stream>>>(
      a1, w2, fc2_b, x1, nullptr, out, 8192, 1024, 4096);
}

// Round 7
// 523.198 us; speedup vs baseline: 1.2411x; 1.0195x over previous
//
#include <hip/hip_runtime.h>
#include <math.h>
#include <stdint.h>

typedef __bf16 bf16_t;
typedef __bf16 bf16x8 __attribute__((ext_vector_type(8)));
typedef float f32x4 __attribute__((ext_vector_type(4)));
typedef unsigned short ushort8_t __attribute__((ext_vector_type(8)));
typedef unsigned short ushort4_t __attribute__((ext_vector_type(4)));

#define LOG2E 1.44269504088896340736f

__device__ inline unsigned short f2bf_bits(float f) {
  union { float f; unsigned int u; } v; v.f = f;
  unsigned int u = v.u;
  return (unsigned short)((u + 0x7fffu + ((u >> 16) & 1u)) >> 16);
}

// global -> LDS direct copy, 16B per lane. LDS dest is wave-uniform base
// + lane*16 (HW behavior, m104); global src is per-lane.
__device__ inline void gld_lds16(const void* g, void* l) {
  __builtin_amdgcn_global_load_lds(
      (__attribute__((address_space(1))) void*)(uintptr_t)(g),
      (__attribute__((address_space(3))) void*)(uintptr_t)(l),
      16, 0, 0);
}

#define BAR() __builtin_amdgcn_s_barrier()
#define LGKM0() asm volatile("s_waitcnt lgkmcnt(0)" ::: "memory")
#define VMW(n) asm volatile("s_waitcnt vmcnt(" #n ")" ::: "memory")
#define PRIO(p) __builtin_amdgcn_s_setprio(p)

// ---------------- cast fp32 -> bf16 (weights) ----------------
__global__ __launch_bounds__(256) void cast_kernel(const float* __restrict__ in,
                                                   unsigned short* __restrict__ out,
                                                   int n) {
  int i = (blockIdx.x * 256 + threadIdx.x) * 4;
  if (i >= n) return;
  float4 f = *reinterpret_cast<const float4*>(in + i);
  ushort4_t o;
  o[0] = f2bf_bits(f.x); o[1] = f2bf_bits(f.y);
  o[2] = f2bf_bits(f.z); o[3] = f2bf_bits(f.w);
  *reinterpret_cast<ushort4_t*>(out + i) = o;
}

// ---------------- LayerNorm (C=1024) + cast to bf16 ----------------
__global__ __launch_bounds__(256) void ln_kernel(const float* __restrict__ x,
                                                 const float* __restrict__ g,
                                                 const float* __restrict__ bta,
                                                 unsigned short* __restrict__ out) {
  const int row = blockIdx.x;
  const int c = threadIdx.x * 4;
  const float4 xv = *reinterpret_cast<const float4*>(x + (size_t)row * 1024 + c);
  float s = xv.x + xv.y + xv.z + xv.w;
  float sq = xv.x * xv.x + xv.y * xv.y + xv.z * xv.z + xv.w * xv.w;
#pragma unroll
  for (int xm = 1; xm < 64; xm <<= 1) {
    s += __shfl_xor(s, xm, 64);
    sq += __shfl_xor(sq, xm, 64);
  }
  __shared__ float sh[8];
  const int wave = threadIdx.x >> 6, lane = threadIdx.x & 63;
  if (lane == 0) { sh[wave] = s; sh[4 + wave] = sq; }
  __syncthreads();
  const float ts = sh[0] + sh[1] + sh[2] + sh[3];
  const float tq = sh[4] + sh[5] + sh[6] + sh[7];
  const float mean = ts * (1.0f / 1024.0f);
  const float var = tq * (1.0f / 1024.0f) - mean * mean;
  const float rstd = rsqrtf(var + 1e-5f);
  const float4 gv = *reinterpret_cast<const float4*>(g + c);
  const float4 bv = *reinterpret_cast<const float4*>(bta + c);
  ushort4_t o;
  o[0] = f2bf_bits((xv.x - mean) * rstd * gv.x + bv.x);
  o[1] = f2bf_bits((xv.y - mean) * rstd * gv.y + bv.y);
  o[2] = f2bf_bits((xv.z - mean) * rstd * gv.z + bv.z);
  o[3] = f2bf_bits((xv.w - mean) * rstd * gv.w + bv.w);
  *reinterpret_cast<ushort4_t*>(out + (size_t)row * 1024 + c) = o;
}

// ---------------- GEMM m97 structure (kept for proj / fc2) -----------------
// EPI: 0 = bias -> bf16 out; 1 = bias + residual -> f32 out; 2 = bias+GELU -> bf16
template <int EPI>
__global__ __launch_bounds__(256) void gemm_bt(const unsigned short* __restrict__ A,
                                               const unsigned short* __restrict__ W,
                                               const float* __restrict__ bias,
                                               const float* __restrict__ res,
                                               unsigned short* __restrict__ outb,
                                               float* __restrict__ outf,
                                               int M, int N, int K) {
  __shared__ unsigned short Asb[128 * 32];
  __shared__ unsigned short Bsb[128 * 32];
  const int tid = threadIdx.x;
  const int wave = tid >> 6;
  const int lane = tid & 63;
  const int m0 = blockIdx.y * 128;
  const int n0 = blockIdx.x * 128;
  const int wm = (wave >> 1) * 64;
  const int wn = (wave & 1) * 64;

  f32x4 acc[4][4];
#pragma unroll
  for (int i = 0; i < 4; ++i)
#pragma unroll
    for (int j = 0; j < 4; ++j) { f32x4 z = {0.f, 0.f, 0.f, 0.f}; acc[i][j] = z; }

  for (int kt = 0; kt < K; kt += 32) {
#pragma unroll
    for (int i = 0; i < 2; ++i) {
      const int off = i * 4096 + wave * 1024 + lane * 16;  // byte pos in 8KB tile
      const int r = off >> 6;                              // 64B per row (BK=32)
      const int ce = (off & 63) >> 1;                      // col element
      gld_lds16(A + (size_t)(m0 + r) * K + kt + ce, &Asb[i * 2048 + wave * 512]);
      gld_lds16(W + (size_t)(n0 + r) * K + kt + ce, &Bsb[i * 2048 + wave * 512]);
    }
    __syncthreads();
    bf16x8 af[4], bfr[4];
#pragma unroll
    for (int mi = 0; mi < 4; ++mi)
      af[mi] = *reinterpret_cast<const bf16x8*>(
          &Asb[(wm + mi * 16 + (lane & 15)) * 32 + (lane >> 4) * 8]);
#pragma unroll
    for (int ni = 0; ni < 4; ++ni)
      bfr[ni] = *reinterpret_cast<const bf16x8*>(
          &Bsb[(wn + ni * 16 + (lane & 15)) * 32 + (lane >> 4) * 8]);
#pragma unroll
    for (int mi = 0; mi < 4; ++mi)
#pragma unroll
      for (int ni = 0; ni < 4; ++ni)
        acc[mi][ni] =
            __builtin_amdgcn_mfma_f32_16x16x32_bf16(af[mi], bfr[ni], acc[mi][ni], 0, 0, 0);
    __syncthreads();
  }

#pragma unroll
  for (int ni = 0; ni < 4; ++ni) {
    const int col = n0 + wn + ni * 16 + (lane & 15);
    const float bv = bias[col];
#pragma unroll
    for (int mi = 0; mi < 4; ++mi) {
#pragma unroll
      for (int r = 0; r < 4; ++r) {
        const int row = m0 + wm + mi * 16 + ((lane >> 4) << 2) + r;
        const size_t idx = (size_t)row * N + col;
        const float v = acc[mi][ni][r] + bv;
        if (EPI == 0) {
          outb[idx] = f2bf_bits(v);
        } else if (EPI == 1) {
          outf[idx] = v + res[idx];
        } else {
          const float gl = 0.5f * v * (1.0f + erff(v * 0.70710678118654752f));
          outb[idx] = f2bf_bits(gl);
        }
      }
    }
  }
}

// ---------------- GEMM 256x256 8-phase (T2+T3+T4+T5), out = A@W^T + bias ----
// 512 threads = 8 waves (2M x 4N), per-wave 128x64 output, acc[8][4] f32x4.
// BK=64; LDS = 2 slots x {A,B} x 2 halves x (128x64 bf16) = 128 KiB ring.
// R6 fixes vs R5:
//  (a) __launch_bounds__(512) only — the (512,2) clause capped VGPR at 128
//      while live state is ~244 (acc=128 + frags=96 + addr) -> 120 MB spill
//      traffic (WRITE_SIZE 183MB, MfmaUtil 17%). LDS already limits to
//      1 block/CU, so the cap bought nothing. 256-VGPR cap fits.
//  (b) full 3-bit XOR swizzle (row&7)<<4 bytes (was 1-bit -> 8-way conflict,
//      6.3M SQ_LDS_BANK_CONFLICT). 16 rows -> 8 slots -> 2-way = free (m136).
//      Same involution both sides (rule #21): read cb ^= (row&7)<<4;
//      stage source col = ((l&7) ^ ((l>>3)&7)) << 3 elements.
// Per phase: {ds_read quadrant frags | stage 1 half-tile} barrier lgkm(0)
// setprio(1) 16xMFMA setprio(0) barrier. vmcnt(4) ONLY at phases 4/8 (T4).
#define MMA16(QM, QN, AF, BF)                                                 \
  do {                                                                        \
    _Pragma("unroll") for (int mi_ = 0; mi_ < 4; ++mi_)                       \
    _Pragma("unroll") for (int ni_ = 0; ni_ < 2; ++ni_)                       \
    _Pragma("unroll") for (int kh_ = 0; kh_ < 2; ++kh_)                       \
      acc[(QM) * 4 + mi_][(QN) * 2 + ni_] =                                   \
          __builtin_amdgcn_mfma_f32_16x16x32_bf16(                            \
              AF[mi_][kh_], BF[ni_][kh_],                                     \
              acc[(QM) * 4 + mi_][(QN) * 2 + ni_], 0, 0, 0);                  \
  } while (0)

#define LDA4(DST, BASE, QM)                                                   \
  do {                                                                        \
    _Pragma("unroll") for (int mi_ = 0; mi_ < 4; ++mi_)                       \
    _Pragma("unroll") for (int kh_ = 0; kh_ < 2; ++kh_) {                     \
      const int row_ = ((QM) * 4 + mi_) * 16 + lr16;                          \
      const int cb_ = (kh_ * 64 + lk * 16) ^ ((row_ & 7) << 4);               \
      DST[mi_][kh_] =                                                         \
          *reinterpret_cast<const bf16x8*>(&lds[(BASE) + row_ * 64 + (cb_ >> 1)]); \
    }                                                                         \
  } while (0)

#define LDB2(DST, BASE, QN)                                                   \
  do {                                                                        \
    _Pragma("unroll") for (int ni_ = 0; ni_ < 2; ++ni_)                       \
    _Pragma("unroll") for (int kh_ = 0; kh_ < 2; ++kh_) {                     \
      const int row_ = (wn & 1) * 64 + ((QN) * 2 + ni_) * 16 + lr16;          \
      const int cb_ = (kh_ * 64 + lk * 16) ^ ((row_ & 7) << 4);               \
      DST[ni_][kh_] =                                                         \
          *reinterpret_cast<const bf16x8*>(&lds[(BASE) + row_ * 64 + (cb_ >> 1)]); \
    }                                                                         \
  } while (0)

template <int EPI>  // 0 = bias->bf16, 2 = bias+GELU->bf16
__global__ __launch_bounds__(512) void gemm256(const unsigned short* __restrict__ A,
                                               const unsigned short* __restrict__ W,
                                               const float* __restrict__ bias,
                                               unsigned short* __restrict__ outb,
                                               int N, int K) {
  __shared__ unsigned short lds[65536];  // 128 KiB
  const int tid = threadIdx.x;
  const int w = tid >> 6;
  const int l = tid & 63;
  const int m0 = blockIdx.y * 256;
  const int n0 = blockIdx.x * 256;
  const int wm = w >> 2;  // 0..1
  const int wn = w & 3;   // 0..3
  const int lr16 = l & 15;
  const int lk = l >> 4;  // 0..3

  // staging per-lane geometry: linear dest off = i*8192 + w*1024 + l*16 bytes
  // -> row = i*64 + w*8 + (l>>3); row&7 = (l>>3)&7. Source col pre-swizzled
  // with the SAME involution the reads apply: elem ^= ((row&7)<<3).
  const int srow = l >> 3;
  const int scol = (((l & 7) ^ ((l >> 3) & 7)) << 3);  // element offset

  auto stageA = [&](int t, int h) {
    const int s_ = t & 1;
#pragma unroll
    for (int i = 0; i < 2; ++i)
      gld_lds16(A + (size_t)(m0 + h * 128 + i * 64 + w * 8 + srow) * K + t * 64 + scol,
                &lds[(s_ * 2 + h) * 8192 + i * 4096 + w * 512]);
  };
  auto stageB = [&](int t, int h) {
    const int s_ = t & 1;
#pragma unroll
    for (int i = 0; i < 2; ++i)
      gld_lds16(W + (size_t)(n0 + h * 128 + i * 64 + w * 8 + srow) * K + t * 64 + scol,
                &lds[(4 + s_ * 2 + h) * 8192 + i * 4096 + w * 512]);
  };

  const int abase0 = wm * 8192;            // A slot0, half wm
  const int abase1 = (2 + wm) * 8192;      // A slot1
  const int bbase0 = (4 + (wn >> 1)) * 8192;
  const int bbase1 = (6 + (wn >> 1)) * 8192;

  f32x4 acc[8][4];
#pragma unroll
  for (int i = 0; i < 8; ++i)
#pragma unroll
    for (int j = 0; j < 4; ++j) { f32x4 z = {0.f, 0.f, 0.f, 0.f}; acc[i][j] = z; }

  bf16x8 a0[4][2], a1[4][2], b0[2][2], b1[2][2];

  // prologue: tile0 (A,B) + tile1 A; vmcnt(4) leaves A(1) in flight
  stageA(0, 0); stageA(0, 1);
  stageB(0, 0); stageB(0, 1);
  stageA(1, 0); stageA(1, 1);
  VMW(4);
  BAR();

  const int nt = K / 64;  // even (K multiple of 128)
  for (int t0 = 0; t0 < nt; t0 += 2) {
    const int t1 = t0 + 1;
    const int tn0 = (t0 + 2 < nt) ? (t0 + 2) : 0;  // clamp keeps even parity
    const int tn1 = (t0 + 3 < nt) ? (t0 + 3) : 1;  // clamp keeps odd parity

    // ph1: slot0 q(0,0); stage B(t1)h0   [B-slot1 last read prev ph7]
    LDA4(a0, abase0, 0);
    LDB2(b0, bbase0, 0);
    stageB(t1, 0);
    BAR(); LGKM0(); PRIO(1); MMA16(0, 0, a0, b0); PRIO(0); BAR();
    // ph2: slot0 q(1,0); stage B(t1)h1
    LDA4(a1, abase0, 1);
    stageB(t1, 1);
    BAR(); LGKM0(); PRIO(1); MMA16(1, 0, a1, b0); PRIO(0); BAR();
    // ph3: slot0 q(1,1); stage A(t0+2)h0  [A-slot0 reads ended ph2]
    LDB2(b1, bbase0, 1);
    stageA(tn0, 0);
    BAR(); LGKM0(); PRIO(1); MMA16(1, 1, a1, b1); PRIO(0); BAR();
    // ph4: slot0 q(0,1); stage A(t0+2)h1; vmcnt(4) -> slot1 (A prev ph7/8,
    // B this ph1/2) fully landed before ph5 reads
    stageA(tn0, 1);
    BAR(); LGKM0(); PRIO(1); MMA16(0, 1, a0, b1); PRIO(0);
    VMW(4);
    BAR();
    // ph5: slot1 q(0,0); stage B(t0+2)h0  [B-slot0 reads ended ph3]
    LDA4(a0, abase1, 0);
    LDB2(b0, bbase1, 0);
    stageB(tn0, 0);
    BAR(); LGKM0(); PRIO(1); MMA16(0, 0, a0, b0); PRIO(0); BAR();
    // ph6: slot1 q(1,0); stage B(t0+2)h1
    LDA4(a1, abase1, 1);
    stageB(tn0, 1);
    BAR(); LGKM0(); PRIO(1); MMA16(1, 0, a1, b0); PRIO(0); BAR();
    // ph7: slot1 q(1,1); stage A(t1+2)h0  [A-slot1 reads ended ph6]
    LDB2(b1, bbase1, 1);
    stageA(tn1, 0);
    BAR(); LGKM0(); PRIO(1); MMA16(1, 1, a1, b1); PRIO(0); BAR();
    // ph8: slot1 q(0,1); stage A(t1+2)h1; vmcnt(4) -> slot0 (ph3..6) landed
    stageA(tn1, 1);
    BAR(); LGKM0(); PRIO(1); MMA16(0, 1, a0, b1); PRIO(0);
    VMW(4);
    BAR();
  }
  VMW(0);  // drain dangling prefetches before LDS reuse/exit

  // epilogue: C row=(l>>4)*4+r, col=l&15 per 16x16 fragment (m89/m91)
#pragma unroll
  for (int ni = 0; ni < 4; ++ni) {
    const int col = n0 + wn * 64 + ni * 16 + lr16;
    const float bv = bias[col];
#pragma unroll
    for (int mi = 0; mi < 8; ++mi) {
#pragma unroll
      for (int r = 0; r < 4; ++r) {
        const int row = m0 + wm * 128 + mi * 16 + lk * 4 + r;
        float v = acc[mi][ni][r] + bv;
        if (EPI == 2) v = 0.5f * v * (1.0f + erff(v * 0.70710678118654752f));
        outb[(size_t)row * N + col] = f2bf_bits(v);
      }
    }
  }
}

// ---------------- causal flash attention v2 (paired q-tiles) ----------------
// Paired q-tiles (lo=pair, hi=15-pair): uniform 17 compute-iters/block, zero
// causal tail. No min-waves clause (R5 lesson: forced VGPR 64 -> 750MB spill).
__device__ inline int swz(int row, int colelem) {
  return row * 64 + (colelem ^ ((row & 7) << 3));
}

__global__ __launch_bounds__(256) void attn_kernel(const unsigned short* __restrict__ kqv,
                                                   unsigned short* __restrict__ y) {
  __shared__ unsigned short Ks[2][64 * 64];
  __shared__ unsigned short Vt[2][64 * 64];
  __shared__ unsigned short Ps[4][16 * 64];

  const int tid = threadIdx.x;
  const int wave = tid >> 6;
  const int lane = tid & 63;
  const int bh = blockIdx.x;
  const int pair = blockIdx.y;
  const int b = bh >> 4;
  const int h = bh & 15;
  const int lo = pair;
  const int hi = 15 - pair;
  const int bT = b * 1024;
  const int hoff = h * 192;

  auto loadq = [&](int q0t, bf16x8 (&qf)[2]) {
    const unsigned short* qp =
        kqv + (size_t)(bT + q0t + wave * 16 + (lane & 15)) * 3072 + hoff + 64 +
        (lane >> 4) * 8;
#pragma unroll
    for (int kk = 0; kk < 2; ++kk) {
      bf16x8 t = *reinterpret_cast<const bf16x8*>(qp + kk * 32);
#pragma unroll
      for (int e = 0; e < 8; ++e) t[e] = (bf16_t)((float)t[e] * 0.125f);
      qf[kk] = t;
    }
  };

  auto stageK = [&](int j0, int bufi) {
#pragma unroll
    for (int i = 0; i < 2; ++i) {
      const int off = i * 4096 + wave * 1024 + lane * 16;
      const int jr = off >> 7;
      const int ce = ((off & 127) >> 1) ^ ((jr & 7) << 3);
      gld_lds16(kqv + (size_t)(bT + j0 + jr) * 3072 + hoff + ce,
                &Ks[bufi][i * 2048 + wave * 512]);
    }
  };

  ushort8_t vreg0, vreg1;
  auto vload = [&](int j0) {
    const unsigned short* vp =
        kqv + (size_t)(bT + j0 + (tid & 63)) * 3072 + hoff + 128 + (tid >> 6) * 8;
    vreg0 = *reinterpret_cast<const ushort8_t*>(vp);
    vreg1 = *reinterpret_cast<const ushort8_t*>(vp + 32);
  };
  auto vwrite = [&](int bufi) {
    const int j = tid & 63;
    const int dg = tid >> 6;
#pragma unroll
    for (int e = 0; e < 8; ++e) Vt[bufi][swz(dg * 8 + e, j)] = vreg0[e];
#pragma unroll
    for (int e = 0; e < 8; ++e) Vt[bufi][swz((dg + 4) * 8 + e, j)] = vreg1[e];
  };

  auto compute = [&](const bf16x8 (&qf)[2], f32x4 (&acc_o)[4], float (&mr)[4],
                     float (&lr)[4], int q0t, int j0, bool diag, int cur) {
    f32x4 s[4];
#pragma unroll
    for (int nt = 0; nt < 4; ++nt) {
      f32x4 a = {0.f, 0.f, 0.f, 0.f};
#pragma unroll
      for (int kk = 0; kk < 2; ++kk) {
        const bf16x8 kf = *reinterpret_cast<const bf16x8*>(
            &Ks[cur][swz(nt * 16 + (lane & 15), kk * 32 + (lane >> 4) * 8)]);
        a = __builtin_amdgcn_mfma_f32_16x16x32_bf16(qf[kk], kf, a, 0, 0, 0);
      }
      s[nt] = a;
    }
#pragma unroll
    for (int r = 0; r < 4; ++r) {
      float mx = -1e30f;
      if (diag) {
        const int qg = q0t + wave * 16 + ((lane >> 4) << 2) + r;
#pragma unroll
        for (int nt = 0; nt < 4; ++nt) {
          const int jg = j0 + nt * 16 + (lane & 15);
          const float sv = (jg <= qg) ? s[nt][r] : -1e30f;
          s[nt][r] = sv;
          mx = fmaxf(mx, sv);
        }
      } else {
#pragma unroll
        for (int nt = 0; nt < 4; ++nt) mx = fmaxf(mx, s[nt][r]);
      }
#pragma unroll
      for (int xm = 1; xm < 16; xm <<= 1) mx = fmaxf(mx, __shfl_xor(mx, xm, 64));
      const float mnew = fmaxf(mr[r], mx);
      const float sc = exp2f((mr[r] - mnew) * LOG2E);
      mr[r] = mnew;
      float ssum = 0.f;
#pragma unroll
      for (int nt = 0; nt < 4; ++nt) {
        const float p = exp2f((s[nt][r] - mnew) * LOG2E);
        s[nt][r] = p;
        ssum += p;
      }
#pragma unroll
      for (int xm = 1; xm < 16; xm <<= 1) ssum += __shfl_xor(ssum, xm, 64);
      lr[r] = lr[r] * sc + ssum;
#pragma unroll
      for (int dt = 0; dt < 4; ++dt) acc_o[dt][r] *= sc;
    }
    unsigned short* Pw = &Ps[wave][0];
#pragma unroll
    for (int nt = 0; nt < 4; ++nt)
#pragma unroll
      for (int r = 0; r < 4; ++r)
        Pw[swz(((lane >> 4) << 2) + r, nt * 16 + (lane & 15))] = f2bf_bits(s[nt][r]);
#pragma unroll
    for (int kk = 0; kk < 2; ++kk) {
      const bf16x8 pf = *reinterpret_cast<const bf16x8*>(
          &Ps[wave][swz(lane & 15, kk * 32 + (lane >> 4) * 8)]);
#pragma unroll
      for (int dt = 0; dt < 4; ++dt) {
        const bf16x8 vf = *reinterpret_cast<const bf16x8*>(
            &Vt[cur][swz(dt * 16 + (lane & 15), kk * 32 + (lane >> 4) * 8)]);
        acc_o[dt] = __builtin_amdgcn_mfma_f32_16x16x32_bf16(pf, vf, acc_o[dt], 0, 0, 0);
      }
    }
  };

  auto writeo = [&](int q0t, f32x4 (&acc_o)[4], float (&lr)[4]) {
#pragma unroll
    for (int dt = 0; dt < 4; ++dt)
#pragma unroll
      for (int r = 0; r < 4; ++r) {
        const int qg = q0t + wave * 16 + ((lane >> 4) << 2) + r;
        y[(size_t)(bT + qg) * 1024 + h * 64 + dt * 16 + (lane & 15)] =
            f2bf_bits(acc_o[dt][r] / lr[r]);
      }
  };

  bf16x8 qf_l[2], qf_h[2];
  loadq(lo * 64, qf_l);
  loadq(hi * 64, qf_h);
  f32x4 acc_l[4], acc_h[4];
#pragma unroll
  for (int dt = 0; dt < 4; ++dt) {
    f32x4 z = {0.f, 0.f, 0.f, 0.f};
    acc_l[dt] = z;
    acc_h[dt] = z;
  }
  float mr_l[4] = {-1e30f, -1e30f, -1e30f, -1e30f};
  float mr_h[4] = {-1e30f, -1e30f, -1e30f, -1e30f};
  float lr_l[4] = {0.f, 0.f, 0.f, 0.f};
  float lr_h[4] = {0.f, 0.f, 0.f, 0.f};

  stageK(0, 0);
  vload(0);
  vwrite(0);

  for (int jt = 0; jt <= hi; ++jt) {
    const int cur = jt & 1;
    __syncthreads();  // drains vmcnt/lgkm: buf[cur] ready; buf[cur^1] free
    if (jt < hi) {
      stageK((jt + 1) * 64, cur ^ 1);
      vload((jt + 1) * 64);
    }
    compute(qf_h, acc_h, mr_h, lr_h, hi * 64, jt * 64, jt == hi, cur);
    if (jt <= lo)
      compute(qf_l, acc_l, mr_l, lr_l, lo * 64, jt * 64, jt == lo, cur);
    if (jt < hi) vwrite(cur ^ 1);
  }

  writeo(hi * 64, acc_h, lr_h);
  writeo(lo * 64, acc_l, lr_l);
}

// ---------------- launch ----------------
extern "C" void kernel_launch(void* const* d_in, const int* in_sizes, int n_in,
                              void* d_out, int out_size, void* d_ws, size_t ws_size,
                              hipStream_t stream) {
  const float* x = (const float*)d_in[0];
  const float* kqv_w = (const float*)d_in[1];
  const float* kqv_b = (const float*)d_in[2];
  const float* proj_w = (const float*)d_in[3];
  const float* proj_b = (const float*)d_in[4];
  const float* ln1_g = (const float*)d_in[5];
  const float* ln1_b = (const float*)d_in[6];
  const float* ln2_g = (const float*)d_in[7];
  const float* ln2_b = (const float*)d_in[8];
  const float* fc1_w = (const float*)d_in[9];
  const float* fc1_b = (const float*)d_in[10];
  const float* fc2_w = (const float*)d_in[11];
  const float* fc2_b = (const float*)d_in[12];
  float* out = (float*)d_out;

  char* ws = (char*)d_ws;
  size_t off = 0;
  auto alloc = [&](size_t bytes) {
    char* p = ws + off;
    off += (bytes + 255) & ~(size_t)255;
    return p;
  };
  unsigned short* wk = (unsigned short*)alloc((size_t)3072 * 1024 * 2);
  unsigned short* wp = (unsigned short*)alloc((size_t)1024 * 1024 * 2);
  unsigned short* w1 = (unsigned short*)alloc((size_t)4096 * 1024 * 2);
  unsigned short* w2 = (unsigned short*)alloc((size_t)4096 * 1024 * 2);
  unsigned short* hbuf = (unsigned short*)alloc((size_t)8192 * 1024 * 2);
  unsigned short* kqvb = (unsigned short*)alloc((size_t)8192 * 3072 * 2);
  unsigned short* yb = (unsigned short*)alloc((size_t)8192 * 1024 * 2);
  float* x1 = (float*)alloc((size_t)8192 * 1024 * 4);
  unsigned short* a1 = (unsigned short*)alloc((size_t)8192 * 4096 * 2);

  // cast weights to bf16
  cast_kernel<<<dim3(3072 * 1024 / 1024), 256, 0, stream>>>(kqv_w, wk, 3072 * 1024);
  cast_kernel<<<dim3(1024 * 1024 / 1024), 256, 0, stream>>>(proj_w, wp, 1024 * 1024);
  cast_kernel<<<dim3(4096 * 1024 / 1024), 256, 0, stream>>>(fc1_w, w1, 4096 * 1024);
  cast_kernel<<<dim3(4096 * 1024 / 1024), 256, 0, stream>>>(fc2_w, w2, 4096 * 1024);

  // LN1 -> h (bf16)
  ln_kernel<<<dim3(8192), 256, 0, stream>>>(x, ln1_g, ln1_b, hbuf);

  // kqv = h @ kqv_w^T + b   [8192 x 3072]   (8-phase 256^2)
  gemm256<0><<<dim3(3072 / 256, 8192 / 256), 512, 0, stream>>>(
      hbuf, wk, kqv_b, kqvb, 3072, 1024);

  // attention -> y (bf16)
  attn_kernel<<<dim3(128, 8), 256, 0, stream>>>(kqvb, yb);

  // x1 = x + y @ proj_w^T + b   (fp32)  (m97 128^2: N=1024 grid too small for 256^2)
  gemm_bt<1><<<dim3(1024 / 128, 8192 / 128), 256, 0, stream>>>(
      yb, wp, proj_b, x, nullptr, x1, 8192, 1024, 1024);

  // LN2 -> h (bf16, reuse)
  ln_kernel<<<dim3(8192), 256, 0, stream>>>(x1, ln2_g, ln2_b, hbuf);

  // a1 = gelu(h @ fc1_w^T + b)  [8192 x 4096] bf16   (8-phase 256^2)
  gemm256<2><<<dim3(4096 / 256, 8192 / 256), 512, 0, stream>>>(
      hbuf, w1, fc1_b, a1, 4096, 1024);

  // out = x1 + a1 @ fc2_w^T + b  (fp32)  (m97 128^2: N=1024)
  gemm_bt<1><<<dim3(1024 / 128, 8192 / 128), 256, 0, stream>>>(
      a1, w2, fc2_b, x1, nullptr, out, 8192, 1024, 4096);
}

// Round 8
// 510.487 us; speedup vs baseline: 1.2720x; 1.0249x over previous
//
#include <hip/hip_runtime.h>
#include <math.h>
#include <stdint.h>

typedef __bf16 bf16_t;
typedef __bf16 bf16x8 __attribute__((ext_vector_type(8)));
typedef float f32x4 __attribute__((ext_vector_type(4)));
typedef unsigned short ushort8_t __attribute__((ext_vector_type(8)));
typedef unsigned short ushort4_t __attribute__((ext_vector_type(4)));

#define LOG2E 1.44269504088896340736f

__device__ inline unsigned short f2bf_bits(float f) {
  union { float f; unsigned int u; } v; v.f = f;
  unsigned int u = v.u;
  return (unsigned short)((u + 0x7fffu + ((u >> 16) & 1u)) >> 16);
}

// global -> LDS direct copy, 16B per lane. LDS dest is wave-uniform base
// + lane*16 (HW behavior, m104); global src is per-lane.
__device__ inline void gld_lds16(const void* g, void* l) {
  __builtin_amdgcn_global_load_lds(
      (__attribute__((address_space(1))) void*)(uintptr_t)(g),
      (__attribute__((address_space(3))) void*)(uintptr_t)(l),
      16, 0, 0);
}

#define BAR() __builtin_amdgcn_s_barrier()
#define LGKM0() asm volatile("s_waitcnt lgkmcnt(0)" ::: "memory")
#define VMW(n) asm volatile("s_waitcnt vmcnt(" #n ")" ::: "memory")
#define PRIO(p) __builtin_amdgcn_s_setprio(p)

// ---------------- cast fp32 -> bf16 (weights) ----------------
__global__ __launch_bounds__(256) void cast_kernel(const float* __restrict__ in,
                                                   unsigned short* __restrict__ out,
                                                   int n) {
  int i = (blockIdx.x * 256 + threadIdx.x) * 4;
  if (i >= n) return;
  float4 f = *reinterpret_cast<const float4*>(in + i);
  ushort4_t o;
  o[0] = f2bf_bits(f.x); o[1] = f2bf_bits(f.y);
  o[2] = f2bf_bits(f.z); o[3] = f2bf_bits(f.w);
  *reinterpret_cast<ushort4_t*>(out + i) = o;
}

// ---------------- LayerNorm (C=1024) + cast to bf16 ----------------
__global__ __launch_bounds__(256) void ln_kernel(const float* __restrict__ x,
                                                 const float* __restrict__ g,
                                                 const float* __restrict__ bta,
                                                 unsigned short* __restrict__ out) {
  const int row = blockIdx.x;
  const int c = threadIdx.x * 4;
  const float4 xv = *reinterpret_cast<const float4*>(x + (size_t)row * 1024 + c);
  float s = xv.x + xv.y + xv.z + xv.w;
  float sq = xv.x * xv.x + xv.y * xv.y + xv.z * xv.z + xv.w * xv.w;
#pragma unroll
  for (int xm = 1; xm < 64; xm <<= 1) {
    s += __shfl_xor(s, xm, 64);
    sq += __shfl_xor(sq, xm, 64);
  }
  __shared__ float sh[8];
  const int wave = threadIdx.x >> 6, lane = threadIdx.x & 63;
  if (lane == 0) { sh[wave] = s; sh[4 + wave] = sq; }
  __syncthreads();
  const float ts = sh[0] + sh[1] + sh[2] + sh[3];
  const float tq = sh[4] + sh[5] + sh[6] + sh[7];
  const float mean = ts * (1.0f / 1024.0f);
  const float var = tq * (1.0f / 1024.0f) - mean * mean;
  const float rstd = rsqrtf(var + 1e-5f);
  const float4 gv = *reinterpret_cast<const float4*>(g + c);
  const float4 bv = *reinterpret_cast<const float4*>(bta + c);
  ushort4_t o;
  o[0] = f2bf_bits((xv.x - mean) * rstd * gv.x + bv.x);
  o[1] = f2bf_bits((xv.y - mean) * rstd * gv.y + bv.y);
  o[2] = f2bf_bits((xv.z - mean) * rstd * gv.z + bv.z);
  o[3] = f2bf_bits((xv.w - mean) * rstd * gv.w + bv.w);
  *reinterpret_cast<ushort4_t*>(out + (size_t)row * 1024 + c) = o;
}

// ---------------- GEMM m97 structure (kept for proj / fc2) -----------------
// EPI: 0 = bias -> bf16 out; 1 = bias + residual -> f32 out; 2 = bias+GELU -> bf16
template <int EPI>
__global__ __launch_bounds__(256) void gemm_bt(const unsigned short* __restrict__ A,
                                               const unsigned short* __restrict__ W,
                                               const float* __restrict__ bias,
                                               const float* __restrict__ res,
                                               unsigned short* __restrict__ outb,
                                               float* __restrict__ outf,
                                               int M, int N, int K) {
  __shared__ unsigned short Asb[128 * 32];
  __shared__ unsigned short Bsb[128 * 32];
  const int tid = threadIdx.x;
  const int wave = tid >> 6;
  const int lane = tid & 63;
  const int m0 = blockIdx.y * 128;
  const int n0 = blockIdx.x * 128;
  const int wm = (wave >> 1) * 64;
  const int wn = (wave & 1) * 64;

  f32x4 acc[4][4];
#pragma unroll
  for (int i = 0; i < 4; ++i)
#pragma unroll
    for (int j = 0; j < 4; ++j) { f32x4 z = {0.f, 0.f, 0.f, 0.f}; acc[i][j] = z; }

  for (int kt = 0; kt < K; kt += 32) {
#pragma unroll
    for (int i = 0; i < 2; ++i) {
      const int off = i * 4096 + wave * 1024 + lane * 16;  // byte pos in 8KB tile
      const int r = off >> 6;                              // 64B per row (BK=32)
      const int ce = (off & 63) >> 1;                      // col element
      gld_lds16(A + (size_t)(m0 + r) * K + kt + ce, &Asb[i * 2048 + wave * 512]);
      gld_lds16(W + (size_t)(n0 + r) * K + kt + ce, &Bsb[i * 2048 + wave * 512]);
    }
    __syncthreads();
    bf16x8 af[4], bfr[4];
#pragma unroll
    for (int mi = 0; mi < 4; ++mi)
      af[mi] = *reinterpret_cast<const bf16x8*>(
          &Asb[(wm + mi * 16 + (lane & 15)) * 32 + (lane >> 4) * 8]);
#pragma unroll
    for (int ni = 0; ni < 4; ++ni)
      bfr[ni] = *reinterpret_cast<const bf16x8*>(
          &Bsb[(wn + ni * 16 + (lane & 15)) * 32 + (lane >> 4) * 8]);
#pragma unroll
    for (int mi = 0; mi < 4; ++mi)
#pragma unroll
      for (int ni = 0; ni < 4; ++ni)
        acc[mi][ni] =
            __builtin_amdgcn_mfma_f32_16x16x32_bf16(af[mi], bfr[ni], acc[mi][ni], 0, 0, 0);
    __syncthreads();
  }

#pragma unroll
  for (int ni = 0; ni < 4; ++ni) {
    const int col = n0 + wn + ni * 16 + (lane & 15);
    const float bv = bias[col];
#pragma unroll
    for (int mi = 0; mi < 4; ++mi) {
#pragma unroll
      for (int r = 0; r < 4; ++r) {
        const int row = m0 + wm + mi * 16 + ((lane >> 4) << 2) + r;
        const size_t idx = (size_t)row * N + col;
        const float v = acc[mi][ni][r] + bv;
        if (EPI == 0) {
          outb[idx] = f2bf_bits(v);
        } else if (EPI == 1) {
          outf[idx] = v + res[idx];
        } else {
          const float gl = 0.5f * v * (1.0f + erff(v * 0.70710678118654752f));
          outb[idx] = f2bf_bits(gl);
        }
      }
    }
  }
}

// ---------------- GEMM 256x256 8-phase (T2+T3+T4+T5), out = A@W^T + bias ----
// 512 threads = 8 waves (2M x 4N), per-wave 128x64 output, acc[8][4] f32x4.
// BK=64; LDS = 2 slots x {A,B} x 2 halves x (128x64 bf16) = 128 KiB ring.
// R7 diagnosis: VGPR_Count stuck at 128 with WRITE_SIZE 183MB (fc1 ideal 64MB)
// -> compiler's default occupancy target (4 waves/EU = 128-reg budget) forced
// ~100 regs of spill; launch_bounds sets only a FLOOR on waves. Fixes:
//  (a) amdgpu_waves_per_eu(2,2): pin budget to 256 VGPR. LDS already limits
//      to 1 block/CU (= 2 waves/EU), so max=2 costs nothing.
//  (b) quadrant order q00->q01->q11->q10: peak live frags 96->64 regs
//      (a-frags die before second LDA4; only b_lo spans the 4 phases).
//  (c) deeper staging: every phase issues exactly 2 gld_lds, windows 4-6
//      phases: ph1/2 A(o), ph3/4 B(e+2), ph5/6 A(e+2), ph7/8 B(o+2).
//      12 loads in flight; VMW(4) at ph4/ph8 retires exactly what the next
//      slot needs; every region has a barrier-separated phase between its
//      last ds_read (lgkm0 precedes phase-end barrier) and its overwrite.
#define MMA16(QM, QN, AF, BF)                                                 \
  do {                                                                        \
    _Pragma("unroll") for (int mi_ = 0; mi_ < 4; ++mi_)                       \
    _Pragma("unroll") for (int ni_ = 0; ni_ < 2; ++ni_)                       \
    _Pragma("unroll") for (int kh_ = 0; kh_ < 2; ++kh_)                       \
      acc[(QM) * 4 + mi_][(QN) * 2 + ni_] =                                   \
          __builtin_amdgcn_mfma_f32_16x16x32_bf16(                            \
              AF[mi_][kh_], BF[ni_][kh_],                                     \
              acc[(QM) * 4 + mi_][(QN) * 2 + ni_], 0, 0, 0);                  \
  } while (0)

#define LDA4(DST, BASE, QM)                                                   \
  do {                                                                        \
    _Pragma("unroll") for (int mi_ = 0; mi_ < 4; ++mi_)                       \
    _Pragma("unroll") for (int kh_ = 0; kh_ < 2; ++kh_) {                     \
      const int row_ = ((QM) * 4 + mi_) * 16 + lr16;                          \
      const int cb_ = (kh_ * 64 + lk * 16) ^ ((row_ & 7) << 4);               \
      DST[mi_][kh_] =                                                         \
          *reinterpret_cast<const bf16x8*>(&lds[(BASE) + row_ * 64 + (cb_ >> 1)]); \
    }                                                                         \
  } while (0)

#define LDB2(DST, BASE, QN)                                                   \
  do {                                                                        \
    _Pragma("unroll") for (int ni_ = 0; ni_ < 2; ++ni_)                       \
    _Pragma("unroll") for (int kh_ = 0; kh_ < 2; ++kh_) {                     \
      const int row_ = (wn & 1) * 64 + ((QN) * 2 + ni_) * 16 + lr16;          \
      const int cb_ = (kh_ * 64 + lk * 16) ^ ((row_ & 7) << 4);               \
      DST[ni_][kh_] =                                                         \
          *reinterpret_cast<const bf16x8*>(&lds[(BASE) + row_ * 64 + (cb_ >> 1)]); \
    }                                                                         \
  } while (0)

template <int EPI>  // 0 = bias->bf16, 2 = bias+GELU->bf16
__global__ __launch_bounds__(512)
__attribute__((amdgpu_waves_per_eu(2, 2)))
void gemm256(const unsigned short* __restrict__ A,
             const unsigned short* __restrict__ W,
             const float* __restrict__ bias,
             unsigned short* __restrict__ outb,
             int N, int K) {
  __shared__ unsigned short lds[65536];  // 128 KiB
  const int tid = threadIdx.x;
  const int w = tid >> 6;
  const int l = tid & 63;
  const int m0 = blockIdx.y * 256;
  const int n0 = blockIdx.x * 256;
  const int wm = w >> 2;  // 0..1
  const int wn = w & 3;   // 0..3
  const int lr16 = l & 15;
  const int lk = l >> 4;  // 0..3

  // staging: linear dest off = i*8192 + w*1024 + l*16 bytes ->
  // row = i*64 + w*8 + (l>>3); source col pre-swizzled with the read
  // involution elem ^= ((row&7)<<3).
  const int srow = l >> 3;
  const int scol = (((l & 7) ^ ((l >> 3) & 7)) << 3);  // element offset

  auto stageA = [&](int t, int h) {
    const int s_ = t & 1;
#pragma unroll
    for (int i = 0; i < 2; ++i)
      gld_lds16(A + (size_t)(m0 + h * 128 + i * 64 + w * 8 + srow) * K + t * 64 + scol,
                &lds[(s_ * 2 + h) * 8192 + i * 4096 + w * 512]);
  };
  auto stageB = [&](int t, int h) {
    const int s_ = t & 1;
#pragma unroll
    for (int i = 0; i < 2; ++i)
      gld_lds16(W + (size_t)(n0 + h * 128 + i * 64 + w * 8 + srow) * K + t * 64 + scol,
                &lds[(4 + s_ * 2 + h) * 8192 + i * 4096 + w * 512]);
  };

  const int abase0 = wm * 8192;            // A slot0 (even tiles), half wm
  const int abase1 = (2 + wm) * 8192;      // A slot1 (odd tiles)
  const int bbase0 = (4 + (wn >> 1)) * 8192;
  const int bbase1 = (6 + (wn >> 1)) * 8192;

  f32x4 acc[8][4];
#pragma unroll
  for (int i = 0; i < 8; ++i)
#pragma unroll
    for (int j = 0; j < 4; ++j) { f32x4 z = {0.f, 0.f, 0.f, 0.f}; acc[i][j] = z; }

  bf16x8 a[4][2], a2[4][2], bl[2][2], bh[2][2];

  // prologue: A(0), B(0), B(1); wait A(0)+B(0) landed (leaves B(1) in flight)
  stageA(0, 0); stageA(0, 1);
  stageB(0, 0); stageB(0, 1);
  stageB(1, 0); stageB(1, 1);
  VMW(4);
  BAR();

  const int nt = K / 64;  // even
  for (int e = 0; e < nt; e += 2) {
    const int o = e + 1;
    const int e2 = (e + 2 < nt) ? (e + 2) : 0;  // clamp keeps even parity
    const int o2 = (e + 3 < nt) ? (e + 3) : 1;  // clamp keeps odd parity

    // ---- slot0 = tile e ----
    // ph1: q00; stage A(o)h0 -> slot1-A (last read prev ph7)
    LDA4(a, abase0, 0);
    LDB2(bl, bbase0, 0);
    stageA(o, 0);
    BAR(); LGKM0(); PRIO(1); MMA16(0, 0, a, bl); PRIO(0); BAR();
    // ph2: q01; stage A(o)h1
    LDB2(bh, bbase0, 1);
    stageA(o, 1);
    BAR(); LGKM0(); PRIO(1); MMA16(0, 1, a, bh); PRIO(0); BAR();
    // ph3: q11; stage B(e+2)h0 -> slot0-B (last read ph2)
    LDA4(a2, abase0, 1);
    stageB(e2, 0);
    BAR(); LGKM0(); PRIO(1); MMA16(1, 1, a2, bh); PRIO(0); BAR();
    // ph4: q10 (no ds_read); stage B(e+2)h1; wait -> B(o)[prev ph7/8] and
    // A(o)[ph1/2] landed (leaves B(e+2) 4 in flight)
    stageB(e2, 1);
    BAR(); LGKM0(); PRIO(1); MMA16(1, 0, a2, bl); PRIO(0);
    VMW(4);
    BAR();

    // ---- slot1 = tile o ----
    // ph5: q00; stage A(e+2)h0 -> slot0-A (last read ph3)
    LDA4(a, abase1, 0);
    LDB2(bl, bbase1, 0);
    stageA(e2, 0);
    BAR(); LGKM0(); PRIO(1); MMA16(0, 0, a, bl); PRIO(0); BAR();
    // ph6: q01; stage A(e+2)h1
    LDB2(bh, bbase1, 1);
    stageA(e2, 1);
    BAR(); LGKM0(); PRIO(1); MMA16(0, 1, a, bh); PRIO(0); BAR();
    // ph7: q11; stage B(o+2)h0 -> slot1-B (last read ph6)
    LDA4(a2, abase1, 1);
    stageB(o2, 0);
    BAR(); LGKM0(); PRIO(1); MMA16(1, 1, a2, bh); PRIO(0); BAR();
    // ph8: q10; stage B(o+2)h1; wait -> B(e+2)[ph3/4] and A(e+2)[ph5/6]
    // landed for next ph1 (leaves B(o+2) 4 in flight)
    stageB(o2, 1);
    BAR(); LGKM0(); PRIO(1); MMA16(1, 0, a2, bl); PRIO(0);
    VMW(4);
    BAR();
  }
  VMW(0);  // drain dangling clamp prefetches

  // epilogue: C row=(l>>4)*4+r, col=l&15 per 16x16 fragment (m89/m91)
#pragma unroll
  for (int ni = 0; ni < 4; ++ni) {
    const int col = n0 + wn * 64 + ni * 16 + lr16;
    const float bv = bias[col];
#pragma unroll
    for (int mi = 0; mi < 8; ++mi) {
#pragma unroll
      for (int r = 0; r < 4; ++r) {
        const int row = m0 + wm * 128 + mi * 16 + lk * 4 + r;
        float v = acc[mi][ni][r] + bv;
        if (EPI == 2) v = 0.5f * v * (1.0f + erff(v * 0.70710678118654752f));
        outb[(size_t)row * N + col] = f2bf_bits(v);
      }
    }
  }
}

// ---------------- causal flash attention v2 (paired q-tiles) ----------------
// Paired q-tiles (lo=pair, hi=15-pair): uniform 17 compute-iters/block, zero
// causal tail. No min-waves clause (R5 lesson: forced VGPR 64 -> 750MB spill).
__device__ inline int swz(int row, int colelem) {
  return row * 64 + (colelem ^ ((row & 7) << 3));
}

__global__ __launch_bounds__(256) void attn_kernel(const unsigned short* __restrict__ kqv,
                                                   unsigned short* __restrict__ y) {
  __shared__ unsigned short Ks[2][64 * 64];
  __shared__ unsigned short Vt[2][64 * 64];
  __shared__ unsigned short Ps[4][16 * 64];

  const int tid = threadIdx.x;
  const int wave = tid >> 6;
  const int lane = tid & 63;
  const int bh = blockIdx.x;
  const int pair = blockIdx.y;
  const int b = bh >> 4;
  const int h = bh & 15;
  const int lo = pair;
  const int hi = 15 - pair;
  const int bT = b * 1024;
  const int hoff = h * 192;

  auto loadq = [&](int q0t, bf16x8 (&qf)[2]) {
    const unsigned short* qp =
        kqv + (size_t)(bT + q0t + wave * 16 + (lane & 15)) * 3072 + hoff + 64 +
        (lane >> 4) * 8;
#pragma unroll
    for (int kk = 0; kk < 2; ++kk) {
      bf16x8 t = *reinterpret_cast<const bf16x8*>(qp + kk * 32);
#pragma unroll
      for (int e = 0; e < 8; ++e) t[e] = (bf16_t)((float)t[e] * 0.125f);
      qf[kk] = t;
    }
  };

  auto stageK = [&](int j0, int bufi) {
#pragma unroll
    for (int i = 0; i < 2; ++i) {
      const int off = i * 4096 + wave * 1024 + lane * 16;
      const int jr = off >> 7;
      const int ce = ((off & 127) >> 1) ^ ((jr & 7) << 3);
      gld_lds16(kqv + (size_t)(bT + j0 + jr) * 3072 + hoff + ce,
                &Ks[bufi][i * 2048 + wave * 512]);
    }
  };

  ushort8_t vreg0, vreg1;
  auto vload = [&](int j0) {
    const unsigned short* vp =
        kqv + (size_t)(bT + j0 + (tid & 63)) * 3072 + hoff + 128 + (tid >> 6) * 8;
    vreg0 = *reinterpret_cast<const ushort8_t*>(vp);
    vreg1 = *reinterpret_cast<const ushort8_t*>(vp + 32);
  };
  auto vwrite = [&](int bufi) {
    const int j = tid & 63;
    const int dg = tid >> 6;
#pragma unroll
    for (int e = 0; e < 8; ++e) Vt[bufi][swz(dg * 8 + e, j)] = vreg0[e];
#pragma unroll
    for (int e = 0; e < 8; ++e) Vt[bufi][swz((dg + 4) * 8 + e, j)] = vreg1[e];
  };

  auto compute = [&](const bf16x8 (&qf)[2], f32x4 (&acc_o)[4], float (&mr)[4],
                     float (&lr)[4], int q0t, int j0, bool diag, int cur) {
    f32x4 s[4];
#pragma unroll
    for (int nt = 0; nt < 4; ++nt) {
      f32x4 a = {0.f, 0.f, 0.f, 0.f};
#pragma unroll
      for (int kk = 0; kk < 2; ++kk) {
        const bf16x8 kf = *reinterpret_cast<const bf16x8*>(
            &Ks[cur][swz(nt * 16 + (lane & 15), kk * 32 + (lane >> 4) * 8)]);
        a = __builtin_amdgcn_mfma_f32_16x16x32_bf16(qf[kk], kf, a, 0, 0, 0);
      }
      s[nt] = a;
    }
#pragma unroll
    for (int r = 0; r < 4; ++r) {
      float mx = -1e30f;
      if (diag) {
        const int qg = q0t + wave * 16 + ((lane >> 4) << 2) + r;
#pragma unroll
        for (int nt = 0; nt < 4; ++nt) {
          const int jg = j0 + nt * 16 + (lane & 15);
          const float sv = (jg <= qg) ? s[nt][r] : -1e30f;
          s[nt][r] = sv;
          mx = fmaxf(mx, sv);
        }
      } else {
#pragma unroll
        for (int nt = 0; nt < 4; ++nt) mx = fmaxf(mx, s[nt][r]);
      }
#pragma unroll
      for (int xm = 1; xm < 16; xm <<= 1) mx = fmaxf(mx, __shfl_xor(mx, xm, 64));
      const float mnew = fmaxf(mr[r], mx);
      const float sc = exp2f((mr[r] - mnew) * LOG2E);
      mr[r] = mnew;
      float ssum = 0.f;
#pragma unroll
      for (int nt = 0; nt < 4; ++nt) {
        const float p = exp2f((s[nt][r] - mnew) * LOG2E);
        s[nt][r] = p;
        ssum += p;
      }
#pragma unroll
      for (int xm = 1; xm < 16; xm <<= 1) ssum += __shfl_xor(ssum, xm, 64);
      lr[r] = lr[r] * sc + ssum;
#pragma unroll
      for (int dt = 0; dt < 4; ++dt) acc_o[dt][r] *= sc;
    }
    unsigned short* Pw = &Ps[wave][0];
#pragma unroll
    for (int nt = 0; nt < 4; ++nt)
#pragma unroll
      for (int r = 0; r < 4; ++r)
        Pw[swz(((lane >> 4) << 2) + r, nt * 16 + (lane & 15))] = f2bf_bits(s[nt][r]);
#pragma unroll
    for (int kk = 0; kk < 2; ++kk) {
      const bf16x8 pf = *reinterpret_cast<const bf16x8*>(
          &Ps[wave][swz(lane & 15, kk * 32 + (lane >> 4) * 8)]);
#pragma unroll
      for (int dt = 0; dt < 4; ++dt) {
        const bf16x8 vf = *reinterpret_cast<const bf16x8*>(
            &Vt[cur][swz(dt * 16 + (lane & 15), kk * 32 + (lane >> 4) * 8)]);
        acc_o[dt] = __builtin_amdgcn_mfma_f32_16x16x32_bf16(pf, vf, acc_o[dt], 0, 0, 0);
      }
    }
  };

  auto writeo = [&](int q0t, f32x4 (&acc_o)[4], float (&lr)[4]) {
#pragma unroll
    for (int dt = 0; dt < 4; ++dt)
#pragma unroll
      for (int r = 0; r < 4; ++r) {
        const int qg = q0t + wave * 16 + ((lane >> 4) << 2) + r;
        y[(size_t)(bT + qg) * 1024 + h * 64 + dt * 16 + (lane & 15)] =
            f2bf_bits(acc_o[dt][r] / lr[r]);
      }
  };

  bf16x8 qf_l[2], qf_h[2];
  loadq(lo * 64, qf_l);
  loadq(hi * 64, qf_h);
  f32x4 acc_l[4], acc_h[4];
#pragma unroll
  for (int dt = 0; dt < 4; ++dt) {
    f32x4 z = {0.f, 0.f, 0.f, 0.f};
    acc_l[dt] = z;
    acc_h[dt] = z;
  }
  float mr_l[4] = {-1e30f, -1e30f, -1e30f, -1e30f};
  float mr_h[4] = {-1e30f, -1e30f, -1e30f, -1e30f};
  float lr_l[4] = {0.f, 0.f, 0.f, 0.f};
  float lr_h[4] = {0.f, 0.f, 0.f, 0.f};

  stageK(0, 0);
  vload(0);
  vwrite(0);

  for (int jt = 0; jt <= hi; ++jt) {
    const int cur = jt & 1;
    __syncthreads();  // drains vmcnt/lgkm: buf[cur] ready; buf[cur^1] free
    if (jt < hi) {
      stageK((jt + 1) * 64, cur ^ 1);
      vload((jt + 1) * 64);
    }
    compute(qf_h, acc_h, mr_h, lr_h, hi * 64, jt * 64, jt == hi, cur);
    if (jt <= lo)
      compute(qf_l, acc_l, mr_l, lr_l, lo * 64, jt * 64, jt == lo, cur);
    if (jt < hi) vwrite(cur ^ 1);
  }

  writeo(hi * 64, acc_h, lr_h);
  writeo(lo * 64, acc_l, lr_l);
}

// ---------------- launch ----------------
extern "C" void kernel_launch(void* const* d_in, const int* in_sizes, int n_in,
                              void* d_out, int out_size, void* d_ws, size_t ws_size,
                              hipStream_t stream) {
  const float* x = (const float*)d_in[0];
  const float* kqv_w = (const float*)d_in[1];
  const float* kqv_b = (const float*)d_in[2];
  const float* proj_w = (const float*)d_in[3];
  const float* proj_b = (const float*)d_in[4];
  const float* ln1_g = (const float*)d_in[5];
  const float* ln1_b = (const float*)d_in[6];
  const float* ln2_g = (const float*)d_in[7];
  const float* ln2_b = (const float*)d_in[8];
  const float* fc1_w = (const float*)d_in[9];
  const float* fc1_b = (const float*)d_in[10];
  const float* fc2_w = (const float*)d_in[11];
  const float* fc2_b = (const float*)d_in[12];
  float* out = (float*)d_out;

  char* ws = (char*)d_ws;
  size_t off = 0;
  auto alloc = [&](size_t bytes) {
    char* p = ws + off;
    off += (bytes + 255) & ~(size_t)255;
    return p;
  };
  unsigned short* wk = (unsigned short*)alloc((size_t)3072 * 1024 * 2);
  unsigned short* wp = (unsigned short*)alloc((size_t)1024 * 1024 * 2);
  unsigned short* w1 = (unsigned short*)alloc((size_t)4096 * 1024 * 2);
  unsigned short* w2 = (unsigned short*)alloc((size_t)4096 * 1024 * 2);
  unsigned short* hbuf = (unsigned short*)alloc((size_t)8192 * 1024 * 2);
  unsigned short* kqvb = (unsigned short*)alloc((size_t)8192 * 3072 * 2);
  unsigned short* yb = (unsigned short*)alloc((size_t)8192 * 1024 * 2);
  float* x1 = (float*)alloc((size_t)8192 * 1024 * 4);
  unsigned short* a1 = (unsigned short*)alloc((size_t)8192 * 4096 * 2);

  // cast weights to bf16
  cast_kernel<<<dim3(3072 * 1024 / 1024), 256, 0, stream>>>(kqv_w, wk, 3072 * 1024);
  cast_kernel<<<dim3(1024 * 1024 / 1024), 256, 0, stream>>>(proj_w, wp, 1024 * 1024);
  cast_kernel<<<dim3(4096 * 1024 / 1024), 256, 0, stream>>>(fc1_w, w1, 4096 * 1024);
  cast_kernel<<<dim3(4096 * 1024 / 1024), 256, 0, stream>>>(fc2_w, w2, 4096 * 1024);

  // LN1 -> h (bf16)
  ln_kernel<<<dim3(8192), 256, 0, stream>>>(x, ln1_g, ln1_b, hbuf);

  // kqv = h @ kqv_w^T + b   [8192 x 3072]   (8-phase 256^2)
  gemm256<0><<<dim3(3072 / 256, 8192 / 256), 512, 0, stream>>>(
      hbuf, wk, kqv_b, kqvb, 3072, 1024);

  // attention -> y (bf16)
  attn_kernel<<<dim3(128, 8), 256, 0, stream>>>(kqvb, yb);

  // x1 = x + y @ proj_w^T + b   (fp32)  (m97 128^2: N=1024 grid too small for 256^2)
  gemm_bt<1><<<dim3(1024 / 128, 8192 / 128), 256, 0, stream>>>(
      yb, wp, proj_b, x, nullptr, x1, 8192, 1024, 1024);

  // LN2 -> h (bf16, reuse)
  ln_kernel<<<dim3(8192), 256, 0, stream>>>(x1, ln2_g, ln2_b, hbuf);

  // a1 = gelu(h @ fc1_w^T + b)  [8192 x 4096] bf16   (8-phase 256^2)
  gemm256<2><<<dim3(4096 / 256, 8192 / 256), 512, 0, stream>>>(
      hbuf, w1, fc1_b, a1, 4096, 1024);

  // out = x1 + a1 @ fc2_w^T + b  (fp32)  (m97 128^2: N=1024)
  gemm_bt<1><<<dim3(1024 / 128, 8192 / 128), 256, 0, stream>>>(
      a1, w2, fc2_b, x1, nullptr, out, 8192, 1024, 4096);
}

// Round 9
// 445.522 us; speedup vs baseline: 1.4575x; 1.1458x over previous
//
#include <hip/hip_runtime.h>
#include <math.h>
#include <stdint.h>

typedef __bf16 bf16_t;
typedef __bf16 bf16x8 __attribute__((ext_vector_type(8)));
typedef float f32x4 __attribute__((ext_vector_type(4)));
typedef unsigned short ushort8_t __attribute__((ext_vector_type(8)));
typedef unsigned short ushort4_t __attribute__((ext_vector_type(4)));

#define LOG2E 1.44269504088896340736f

__device__ inline unsigned short f2bf_bits(float f) {
  union { float f; unsigned int u; } v; v.f = f;
  unsigned int u = v.u;
  return (unsigned short)((u + 0x7fffu + ((u >> 16) & 1u)) >> 16);
}

// global -> LDS direct copy, 16B per lane. LDS dest is wave-uniform base
// + lane*16 (HW behavior, m104); global src is per-lane.
__device__ inline void gld_lds16(const void* g, void* l) {
  __builtin_amdgcn_global_load_lds(
      (__attribute__((address_space(1))) void*)(uintptr_t)(g),
      (__attribute__((address_space(3))) void*)(uintptr_t)(l),
      16, 0, 0);
}

#define BAR() __builtin_amdgcn_s_barrier()
#define LGKM0() asm volatile("s_waitcnt lgkmcnt(0)" ::: "memory")
#define VMW(n) asm volatile("s_waitcnt vmcnt(" #n ")" ::: "memory")
#define PRIO(p) __builtin_amdgcn_s_setprio(p)

// ---------------- cast fp32 -> bf16 (weights) ----------------
__global__ __launch_bounds__(256) void cast_kernel(const float* __restrict__ in,
                                                   unsigned short* __restrict__ out,
                                                   int n) {
  int i = (blockIdx.x * 256 + threadIdx.x) * 4;
  if (i >= n) return;
  float4 f = *reinterpret_cast<const float4*>(in + i);
  ushort4_t o;
  o[0] = f2bf_bits(f.x); o[1] = f2bf_bits(f.y);
  o[2] = f2bf_bits(f.z); o[3] = f2bf_bits(f.w);
  *reinterpret_cast<ushort4_t*>(out + i) = o;
}

// ---------------- LayerNorm (C=1024) + cast to bf16 ----------------
__global__ __launch_bounds__(256) void ln_kernel(const float* __restrict__ x,
                                                 const float* __restrict__ g,
                                                 const float* __restrict__ bta,
                                                 unsigned short* __restrict__ out) {
  const int row = blockIdx.x;
  const int c = threadIdx.x * 4;
  const float4 xv = *reinterpret_cast<const float4*>(x + (size_t)row * 1024 + c);
  float s = xv.x + xv.y + xv.z + xv.w;
  float sq = xv.x * xv.x + xv.y * xv.y + xv.z * xv.z + xv.w * xv.w;
#pragma unroll
  for (int xm = 1; xm < 64; xm <<= 1) {
    s += __shfl_xor(s, xm, 64);
    sq += __shfl_xor(sq, xm, 64);
  }
  __shared__ float sh[8];
  const int wave = threadIdx.x >> 6, lane = threadIdx.x & 63;
  if (lane == 0) { sh[wave] = s; sh[4 + wave] = sq; }
  __syncthreads();
  const float ts = sh[0] + sh[1] + sh[2] + sh[3];
  const float tq = sh[4] + sh[5] + sh[6] + sh[7];
  const float mean = ts * (1.0f / 1024.0f);
  const float var = tq * (1.0f / 1024.0f) - mean * mean;
  const float rstd = rsqrtf(var + 1e-5f);
  const float4 gv = *reinterpret_cast<const float4*>(g + c);
  const float4 bv = *reinterpret_cast<const float4*>(bta + c);
  ushort4_t o;
  o[0] = f2bf_bits((xv.x - mean) * rstd * gv.x + bv.x);
  o[1] = f2bf_bits((xv.y - mean) * rstd * gv.y + bv.y);
  o[2] = f2bf_bits((xv.z - mean) * rstd * gv.z + bv.z);
  o[3] = f2bf_bits((xv.w - mean) * rstd * gv.w + bv.w);
  *reinterpret_cast<ushort4_t*>(out + (size_t)row * 1024 + c) = o;
}

// ---------------- GEMM 128x256 8-phase, out = A@W^T + bias ------------------
// R8 restructure: the 256^2/8-wave variant needed ~230 unified regs (acc alone
// 128; gfx950 VGPR+AGPR unified) against a 128 budget -> ~100 regs spilled
// (WRITE_SIZE 170MB vs 64 ideal, MfmaUtil 21%, 3 rounds schedule-insensitive).
// This kernel fits by construction:
//   512 thr = 8 waves (2M x 4N), per-wave 64x64 out: acc[4][4]=64 + af 32 +
//   bf 16 + ~24 addr = ~136 unified << 256 budget @2 waves/SIMD.
// LDS 96KB = 2 slots x (A 128x64 + B 256x64) bf16 -> 1 block/CU.
// Grids are TAIL-FREE: kqv (12,64)=768=3x256, fc1 (16,64)=1024, proj/fc2
// (4,64)=256.
// Schedule (4 phases / 2 K-tiles, 16 MFMA each, T2+T3+T4+T5):
//   ph1: ds af+bf01(slot0), stage B(o)x4;  BAR lgkm0 prio MMA(h0) prio BAR
//   ph2: ds bf23(slot0),    stage A(e2)x2; BAR lgkm0 prio MMA(h1) prio VMW(2) BAR
//   ph3: ds af+bf01(slot1), stage B(e2)x4; BAR lgkm0 prio MMA(h0) prio BAR
//   ph4: ds bf23(slot1),    stage A(o2)x2; BAR lgkm0 prio MMA(h1) prio VMW(2) BAR
// vmcnt(2) counted (1 gld/lane/call): entering ph1 only A(o)x2 outstanding,
// A(e)/B(e) landed. WAR: every stage targets a region whose last ds_read was
// exactly one barrier-phase earlier (B(o)<-prev ph4; A(e2)<-ph1; B(e2)<-ph2;
// A(o2)<-ph3). Swizzle: read elem ^= ((row&7)<<3), pre-swizzled global src
// (involution verified element-wise; measured 0 conflicts in R7/R8).
#define LDAF(SLOT)                                                            \
  do {                                                                        \
    _Pragma("unroll") for (int mi_ = 0; mi_ < 4; ++mi_)                       \
    _Pragma("unroll") for (int kh_ = 0; kh_ < 2; ++kh_) {                     \
      const int row_ = wm * 64 + mi_ * 16 + lr16;                             \
      af[mi_][kh_] = *reinterpret_cast<const bf16x8*>(                        \
          &lds[(SLOT) * AS + row_ * 64 + ((kh_ * 32 + lk * 8) ^ axor)]);      \
    }                                                                         \
  } while (0)

#define LDBF(SLOT, HALF)                                                      \
  do {                                                                        \
    _Pragma("unroll") for (int n2_ = 0; n2_ < 2; ++n2_)                       \
    _Pragma("unroll") for (int kh_ = 0; kh_ < 2; ++kh_) {                     \
      const int row_ = wn * 64 + ((HALF) * 2 + n2_) * 16 + lr16;              \
      bf[n2_][kh_] = *reinterpret_cast<const bf16x8*>(                        \
          &lds[BS0 + (SLOT) * BSS + row_ * 64 + ((kh_ * 32 + lk * 8) ^ axor)]); \
    }                                                                         \
  } while (0)

#define PMMA(HALF)                                                            \
  do {                                                                        \
    _Pragma("unroll") for (int mi_ = 0; mi_ < 4; ++mi_)                       \
    _Pragma("unroll") for (int n2_ = 0; n2_ < 2; ++n2_)                       \
    _Pragma("unroll") for (int kh_ = 0; kh_ < 2; ++kh_)                       \
      acc[mi_][(HALF) * 2 + n2_] = __builtin_amdgcn_mfma_f32_16x16x32_bf16(   \
          af[mi_][kh_], bf[n2_][kh_], acc[mi_][(HALF) * 2 + n2_], 0, 0, 0);   \
  } while (0)

template <int EPI>  // 0 = bias->bf16; 1 = bias+res->f32; 2 = bias+GELU->bf16
__global__ __launch_bounds__(512) void gemm8(const unsigned short* __restrict__ A,
                                             const unsigned short* __restrict__ W,
                                             const float* __restrict__ bias,
                                             const float* __restrict__ res,
                                             unsigned short* __restrict__ outb,
                                             float* __restrict__ outf,
                                             int N, int K) {
  __shared__ unsigned short lds[(2 * 128 + 2 * 256) * 64];  // 96 KiB
  const int tid = threadIdx.x;
  const int w = tid >> 6, l = tid & 63;
  const int m0 = blockIdx.y * 128, n0 = blockIdx.x * 256;
  const int wm = w >> 2, wn = w & 3;
  const int lr16 = l & 15, lk = l >> 4;
  const int axor = (lr16 & 7) << 3;  // read-side XOR (elems); row&7 == lr16&7

  const int AS = 128 * 64;            // A slot stride (shorts)
  const int BS0 = 2 * 128 * 64;       // B region base
  const int BSS = 256 * 64;           // B slot stride

  // staging: dest linear (call h: 64 rows); src col pre-swizzled with the
  // same involution: elem = ((tid&7) ^ (row&7))<<3, row&7 == (tid>>3)&7.
  const int sr = tid >> 3;
  const int sx = ((tid & 7) ^ (sr & 7)) << 3;
  auto stA = [&](int t, int h) {
    gld_lds16(A + (size_t)(m0 + h * 64 + sr) * K + t * 64 + sx,
              &lds[(t & 1) * AS + h * 4096 + tid * 8]);
  };
  auto stB = [&](int t, int c) {
    gld_lds16(W + (size_t)(n0 + c * 64 + sr) * K + t * 64 + sx,
              &lds[BS0 + (t & 1) * BSS + c * 4096 + tid * 8]);
  };

  f32x4 acc[4][4];
#pragma unroll
  for (int i = 0; i < 4; ++i)
#pragma unroll
    for (int j = 0; j < 4; ++j) { f32x4 z = {0.f, 0.f, 0.f, 0.f}; acc[i][j] = z; }
  bf16x8 af[4][2], bf[2][2];

  // prologue: A(0), B(0) -> slot0; A(1) -> slot1; wait A0+B0 (A1 in flight)
  stA(0, 0); stA(0, 1);
  stB(0, 0); stB(0, 1); stB(0, 2); stB(0, 3);
  stA(1, 0); stA(1, 1);
  VMW(2);
  BAR();

  const int nt = K / 64;  // even (K = 1024 or 4096)
  for (int e = 0; e < nt; e += 2) {
    const int o = e + 1;
    const int e2 = (e + 2 < nt) ? (e + 2) : 0;  // clamp keeps parity
    const int o2 = (e + 3 < nt) ? (e + 3) : 1;

    // ph1: tile e half0; stage B(o) -> slot1B (last read prev ph4)
    LDAF(0); LDBF(0, 0);
    stB(o, 0); stB(o, 1); stB(o, 2); stB(o, 3);
    BAR(); LGKM0(); PRIO(1); PMMA(0); PRIO(0); BAR();
    // ph2: tile e half1; stage A(e2) -> slot0A (last read ph1)
    LDBF(0, 1);
    stA(e2, 0); stA(e2, 1);
    BAR(); LGKM0(); PRIO(1); PMMA(1); PRIO(0);
    VMW(2);  // retire A(o)+B(o) for ph3; leaves A(e2)
    BAR();
    // ph3: tile o half0; stage B(e2) -> slot0B (last read ph2)
    LDAF(1); LDBF(1, 0);
    stB(e2, 0); stB(e2, 1); stB(e2, 2); stB(e2, 3);
    BAR(); LGKM0(); PRIO(1); PMMA(0); PRIO(0); BAR();
    // ph4: tile o half1; stage A(o2) -> slot1A (last read ph3)
    LDBF(1, 1);
    stA(o2, 0); stA(o2, 1);
    BAR(); LGKM0(); PRIO(1); PMMA(1); PRIO(0);
    VMW(2);  // retire A(e2)+B(e2) for next ph1; leaves A(o2)
    BAR();
  }
  VMW(0);  // drain dangling clamp prefetches

  // epilogue: C row=(l>>4)*4+r, col=l&15 per 16x16 fragment (m89/m91)
#pragma unroll
  for (int ni = 0; ni < 4; ++ni) {
    const int col = n0 + wn * 64 + ni * 16 + lr16;
    const float bv = bias[col];
#pragma unroll
    for (int mi = 0; mi < 4; ++mi) {
#pragma unroll
      for (int r = 0; r < 4; ++r) {
        const int row = m0 + wm * 64 + mi * 16 + lk * 4 + r;
        const size_t idx = (size_t)row * N + col;
        float v = acc[mi][ni][r] + bv;
        if (EPI == 0) {
          outb[idx] = f2bf_bits(v);
        } else if (EPI == 1) {
          outf[idx] = v + res[idx];
        } else {
          v = 0.5f * v * (1.0f + erff(v * 0.70710678118654752f));
          outb[idx] = f2bf_bits(v);
        }
      }
    }
  }
}

// ---------------- causal flash attention v2 (paired q-tiles) ----------------
// Paired q-tiles (lo=pair, hi=15-pair): uniform 17 compute-iters/block, zero
// causal tail. No min-waves clause (R5 lesson: forced VGPR 64 -> 750MB spill).
__device__ inline int swz(int row, int colelem) {
  return row * 64 + (colelem ^ ((row & 7) << 3));
}

__global__ __launch_bounds__(256) void attn_kernel(const unsigned short* __restrict__ kqv,
                                                   unsigned short* __restrict__ y) {
  __shared__ unsigned short Ks[2][64 * 64];
  __shared__ unsigned short Vt[2][64 * 64];
  __shared__ unsigned short Ps[4][16 * 64];

  const int tid = threadIdx.x;
  const int wave = tid >> 6;
  const int lane = tid & 63;
  const int bh = blockIdx.x;
  const int pair = blockIdx.y;
  const int b = bh >> 4;
  const int h = bh & 15;
  const int lo = pair;
  const int hi = 15 - pair;
  const int bT = b * 1024;
  const int hoff = h * 192;

  auto loadq = [&](int q0t, bf16x8 (&qf)[2]) {
    const unsigned short* qp =
        kqv + (size_t)(bT + q0t + wave * 16 + (lane & 15)) * 3072 + hoff + 64 +
        (lane >> 4) * 8;
#pragma unroll
    for (int kk = 0; kk < 2; ++kk) {
      bf16x8 t = *reinterpret_cast<const bf16x8*>(qp + kk * 32);
#pragma unroll
      for (int e = 0; e < 8; ++e) t[e] = (bf16_t)((float)t[e] * 0.125f);
      qf[kk] = t;
    }
  };

  auto stageK = [&](int j0, int bufi) {
#pragma unroll
    for (int i = 0; i < 2; ++i) {
      const int off = i * 4096 + wave * 1024 + lane * 16;
      const int jr = off >> 7;
      const int ce = ((off & 127) >> 1) ^ ((jr & 7) << 3);
      gld_lds16(kqv + (size_t)(bT + j0 + jr) * 3072 + hoff + ce,
                &Ks[bufi][i * 2048 + wave * 512]);
    }
  };

  ushort8_t vreg0, vreg1;
  auto vload = [&](int j0) {
    const unsigned short* vp =
        kqv + (size_t)(bT + j0 + (tid & 63)) * 3072 + hoff + 128 + (tid >> 6) * 8;
    vreg0 = *reinterpret_cast<const ushort8_t*>(vp);
    vreg1 = *reinterpret_cast<const ushort8_t*>(vp + 32);
  };
  auto vwrite = [&](int bufi) {
    const int j = tid & 63;
    const int dg = tid >> 6;
#pragma unroll
    for (int e = 0; e < 8; ++e) Vt[bufi][swz(dg * 8 + e, j)] = vreg0[e];
#pragma unroll
    for (int e = 0; e < 8; ++e) Vt[bufi][swz((dg + 4) * 8 + e, j)] = vreg1[e];
  };

  auto compute = [&](const bf16x8 (&qf)[2], f32x4 (&acc_o)[4], float (&mr)[4],
                     float (&lr)[4], int q0t, int j0, bool diag, int cur) {
    f32x4 s[4];
#pragma unroll
    for (int nt = 0; nt < 4; ++nt) {
      f32x4 a = {0.f, 0.f, 0.f, 0.f};
#pragma unroll
      for (int kk = 0; kk < 2; ++kk) {
        const bf16x8 kf = *reinterpret_cast<const bf16x8*>(
            &Ks[cur][swz(nt * 16 + (lane & 15), kk * 32 + (lane >> 4) * 8)]);
        a = __builtin_amdgcn_mfma_f32_16x16x32_bf16(qf[kk], kf, a, 0, 0, 0);
      }
      s[nt] = a;
    }
#pragma unroll
    for (int r = 0; r < 4; ++r) {
      float mx = -1e30f;
      if (diag) {
        const int qg = q0t + wave * 16 + ((lane >> 4) << 2) + r;
#pragma unroll
        for (int nt = 0; nt < 4; ++nt) {
          const int jg = j0 + nt * 16 + (lane & 15);
          const float sv = (jg <= qg) ? s[nt][r] : -1e30f;
          s[nt][r] = sv;
          mx = fmaxf(mx, sv);
        }
      } else {
#pragma unroll
        for (int nt = 0; nt < 4; ++nt) mx = fmaxf(mx, s[nt][r]);
      }
#pragma unroll
      for (int xm = 1; xm < 16; xm <<= 1) mx = fmaxf(mx, __shfl_xor(mx, xm, 64));
      const float mnew = fmaxf(mr[r], mx);
      const float sc = exp2f((mr[r] - mnew) * LOG2E);
      mr[r] = mnew;
      float ssum = 0.f;
#pragma unroll
      for (int nt = 0; nt < 4; ++nt) {
        const float p = exp2f((s[nt][r] - mnew) * LOG2E);
        s[nt][r] = p;
        ssum += p;
      }
#pragma unroll
      for (int xm = 1; xm < 16; xm <<= 1) ssum += __shfl_xor(ssum, xm, 64);
      lr[r] = lr[r] * sc + ssum;
#pragma unroll
      for (int dt = 0; dt < 4; ++dt) acc_o[dt][r] *= sc;
    }
    unsigned short* Pw = &Ps[wave][0];
#pragma unroll
    for (int nt = 0; nt < 4; ++nt)
#pragma unroll
      for (int r = 0; r < 4; ++r)
        Pw[swz(((lane >> 4) << 2) + r, nt * 16 + (lane & 15))] = f2bf_bits(s[nt][r]);
#pragma unroll
    for (int kk = 0; kk < 2; ++kk) {
      const bf16x8 pf = *reinterpret_cast<const bf16x8*>(
          &Ps[wave][swz(lane & 15, kk * 32 + (lane >> 4) * 8)]);
#pragma unroll
      for (int dt = 0; dt < 4; ++dt) {
        const bf16x8 vf = *reinterpret_cast<const bf16x8*>(
            &Vt[cur][swz(dt * 16 + (lane & 15), kk * 32 + (lane >> 4) * 8)]);
        acc_o[dt] = __builtin_amdgcn_mfma_f32_16x16x32_bf16(pf, vf, acc_o[dt], 0, 0, 0);
      }
    }
  };

  auto writeo = [&](int q0t, f32x4 (&acc_o)[4], float (&lr)[4]) {
#pragma unroll
    for (int dt = 0; dt < 4; ++dt)
#pragma unroll
      for (int r = 0; r < 4; ++r) {
        const int qg = q0t + wave * 16 + ((lane >> 4) << 2) + r;
        y[(size_t)(bT + qg) * 1024 + h * 64 + dt * 16 + (lane & 15)] =
            f2bf_bits(acc_o[dt][r] / lr[r]);
      }
  };

  bf16x8 qf_l[2], qf_h[2];
  loadq(lo * 64, qf_l);
  loadq(hi * 64, qf_h);
  f32x4 acc_l[4], acc_h[4];
#pragma unroll
  for (int dt = 0; dt < 4; ++dt) {
    f32x4 z = {0.f, 0.f, 0.f, 0.f};
    acc_l[dt] = z;
    acc_h[dt] = z;
  }
  float mr_l[4] = {-1e30f, -1e30f, -1e30f, -1e30f};
  float mr_h[4] = {-1e30f, -1e30f, -1e30f, -1e30f};
  float lr_l[4] = {0.f, 0.f, 0.f, 0.f};
  float lr_h[4] = {0.f, 0.f, 0.f, 0.f};

  stageK(0, 0);
  vload(0);
  vwrite(0);

  for (int jt = 0; jt <= hi; ++jt) {
    const int cur = jt & 1;
    __syncthreads();  // drains vmcnt/lgkm: buf[cur] ready; buf[cur^1] free
    if (jt < hi) {
      stageK((jt + 1) * 64, cur ^ 1);
      vload((jt + 1) * 64);
    }
    compute(qf_h, acc_h, mr_h, lr_h, hi * 64, jt * 64, jt == hi, cur);
    if (jt <= lo)
      compute(qf_l, acc_l, mr_l, lr_l, lo * 64, jt * 64, jt == lo, cur);
    if (jt < hi) vwrite(cur ^ 1);
  }

  writeo(hi * 64, acc_h, lr_h);
  writeo(lo * 64, acc_l, lr_l);
}

// ---------------- launch ----------------
extern "C" void kernel_launch(void* const* d_in, const int* in_sizes, int n_in,
                              void* d_out, int out_size, void* d_ws, size_t ws_size,
                              hipStream_t stream) {
  const float* x = (const float*)d_in[0];
  const float* kqv_w = (const float*)d_in[1];
  const float* kqv_b = (const float*)d_in[2];
  const float* proj_w = (const float*)d_in[3];
  const float* proj_b = (const float*)d_in[4];
  const float* ln1_g = (const float*)d_in[5];
  const float* ln1_b = (const float*)d_in[6];
  const float* ln2_g = (const float*)d_in[7];
  const float* ln2_b = (const float*)d_in[8];
  const float* fc1_w = (const float*)d_in[9];
  const float* fc1_b = (const float*)d_in[10];
  const float* fc2_w = (const float*)d_in[11];
  const float* fc2_b = (const float*)d_in[12];
  float* out = (float*)d_out;

  char* ws = (char*)d_ws;
  size_t off = 0;
  auto alloc = [&](size_t bytes) {
    char* p = ws + off;
    off += (bytes + 255) & ~(size_t)255;
    return p;
  };
  unsigned short* wk = (unsigned short*)alloc((size_t)3072 * 1024 * 2);
  unsigned short* wp = (unsigned short*)alloc((size_t)1024 * 1024 * 2);
  unsigned short* w1 = (unsigned short*)alloc((size_t)4096 * 1024 * 2);
  unsigned short* w2 = (unsigned short*)alloc((size_t)4096 * 1024 * 2);
  unsigned short* hbuf = (unsigned short*)alloc((size_t)8192 * 1024 * 2);
  unsigned short* kqvb = (unsigned short*)alloc((size_t)8192 * 3072 * 2);
  unsigned short* yb = (unsigned short*)alloc((size_t)8192 * 1024 * 2);
  float* x1 = (float*)alloc((size_t)8192 * 1024 * 4);
  unsigned short* a1 = (unsigned short*)alloc((size_t)8192 * 4096 * 2);

  // cast weights to bf16
  cast_kernel<<<dim3(3072 * 1024 / 1024), 256, 0, stream>>>(kqv_w, wk, 3072 * 1024);
  cast_kernel<<<dim3(1024 * 1024 / 1024), 256, 0, stream>>>(proj_w, wp, 1024 * 1024);
  cast_kernel<<<dim3(4096 * 1024 / 1024), 256, 0, stream>>>(fc1_w, w1, 4096 * 1024);
  cast_kernel<<<dim3(4096 * 1024 / 1024), 256, 0, stream>>>(fc2_w, w2, 4096 * 1024);

  // LN1 -> h (bf16)
  ln_kernel<<<dim3(8192), 256, 0, stream>>>(x, ln1_g, ln1_b, hbuf);

  // kqv = h @ kqv_w^T + b   [8192 x 3072]   grid (12,64)=768, tail-free
  gemm8<0><<<dim3(3072 / 256, 8192 / 128), 512, 0, stream>>>(
      hbuf, wk, kqv_b, nullptr, kqvb, nullptr, 3072, 1024);

  // attention -> y (bf16)
  attn_kernel<<<dim3(128, 8), 256, 0, stream>>>(kqvb, yb);

  // x1 = x + y @ proj_w^T + b   (fp32)   grid (4,64)=256, tail-free
  gemm8<1><<<dim3(1024 / 256, 8192 / 128), 512, 0, stream>>>(
      yb, wp, proj_b, x, nullptr, x1, 1024, 1024);

  // LN2 -> h (bf16, reuse)
  ln_kernel<<<dim3(8192), 256, 0, stream>>>(x1, ln2_g, ln2_b, hbuf);

  // a1 = gelu(h @ fc1_w^T + b)  [8192 x 4096]   grid (16,64)=1024, tail-free
  gemm8<2><<<dim3(4096 / 256, 8192 / 128), 512, 0, stream>>>(
      hbuf, w1, fc1_b, nullptr, a1, nullptr, 4096, 1024);

  // out = x1 + a1 @ fc2_w^T + b  (fp32)  grid (4,64)=256, K=4096
  gemm8<1><<<dim3(1024 / 256, 8192 / 128), 512, 0, stream>>>(
      a1, w2, fc2_b, x1, nullptr, out, 1024, 4096);
}